// Round 1
// baseline (237.882 us; speedup 1.0000x reference)
//
#include <hip/hip_runtime.h>
#include <hip/hip_bf16.h>
#include <cstdint>
#include <cstddef>

constexpr int Bn = 4;
constexpr int Nq = 8192;
constexpr int Mk = 2048;
constexpr int C1c = 128;
constexpr int C2c = 256;
constexpr int H1c = 256;
constexpr int H2c = 128;

// ---------------- 3-NN kernel: 4 threads per query ----------------
__global__ __launch_bounds__(256) void knn_kernel(
    const float* __restrict__ unknown,  // (B, Nq, 3)
    const float* __restrict__ known,    // (B, Mk, 3)
    int* __restrict__ idx_out,          // (B, Nq, 3)
    float* __restrict__ w_out)          // (B, Nq, 3)
{
    __shared__ float kx[Mk], ky[Mk], kz[Mk];
    const int b = blockIdx.x / (Nq / 64);
    const int n0 = (blockIdx.x % (Nq / 64)) * 64;
    const int t = threadIdx.x;

    const float* kb = known + (size_t)b * Mk * 3;
    for (int i = t; i < Mk; i += 256) {
        kx[i] = kb[i * 3 + 0];
        ky[i] = kb[i * 3 + 1];
        kz[i] = kb[i * 3 + 2];
    }
    __syncthreads();

    const int q = n0 + (t >> 2);
    const int s = t & 3;
    const float* u = unknown + ((size_t)b * Nq + q) * 3;
    const float ux = u[0], uy = u[1], uz = u[2];

    float d0 = 1e30f, d1 = 1e30f, d2 = 1e30f;
    int i0 = 0, i1 = 0, i2 = 0;

    auto ins = [&](float d, int i) {
        const bool c0 = d < d0, c1 = d < d1, c2 = d < d2;
        d2 = c1 ? d1 : (c2 ? d : d2);
        i2 = c1 ? i1 : (c2 ? i : i2);
        d1 = c0 ? d0 : (c1 ? d : d1);
        i1 = c0 ? i0 : (c1 ? i : i1);
        d0 = c0 ? d : d0;
        i0 = c0 ? i : i0;
    };

    const int mstart = s * (Mk / 4);
    for (int m = mstart; m < mstart + Mk / 4; ++m) {
        const float dx = ux - kx[m], dy = uy - ky[m], dz = uz - kz[m];
        ins(dx * dx + dy * dy + dz * dz, m);
    }

    // butterfly merge over the 4 slice-lanes
    #pragma unroll
    for (int off = 1; off <= 2; off <<= 1) {
        const float e0 = __shfl_xor(d0, off), e1 = __shfl_xor(d1, off), e2 = __shfl_xor(d2, off);
        const int j0 = __shfl_xor(i0, off), j1 = __shfl_xor(i1, off), j2 = __shfl_xor(i2, off);
        ins(e0, j0);
        ins(e1, j1);
        ins(e2, j2);
    }

    if (s == 0) {
        const float r0 = 1.0f / (d0 + 1e-8f);
        const float r1 = 1.0f / (d1 + 1e-8f);
        const float r2 = 1.0f / (d2 + 1e-8f);
        const float inv = 1.0f / (r0 + r1 + r2);
        const size_t base = ((size_t)b * Nq + q) * 3;
        idx_out[base + 0] = i0;
        idx_out[base + 1] = i1;
        idx_out[base + 2] = i2;
        w_out[base + 0] = r0 * inv;
        w_out[base + 1] = r1 * inv;
        w_out[base + 2] = r2 * inv;
    }
}

// ---------------- gather: y1[b,o,n] = sum_k w_k * P[b,o,idx_k] ----------------
__global__ __launch_bounds__(256) void gather_kernel(
    const float* __restrict__ P,      // (B, H1, Mk)
    const int* __restrict__ idx,      // (B, Nq, 3)
    const float* __restrict__ w,      // (B, Nq, 3)
    float* __restrict__ y1)           // (B, H1, Nq)
{
    const int b = blockIdx.x / (Nq / 64);
    const int n0 = (blockIdx.x % (Nq / 64)) * 64;
    const int t = threadIdx.x;
    const int q = n0 + (t & 63);
    const int og = t >> 6;  // 0..3

    const size_t base = ((size_t)b * Nq + q) * 3;
    const int j0 = idx[base + 0], j1 = idx[base + 1], j2 = idx[base + 2];
    const float w0 = w[base + 0], w1 = w[base + 1], w2 = w[base + 2];

    const float* Pb = P + (size_t)b * H1c * Mk;
    float* yb = y1 + (size_t)b * H1c * Nq;
    #pragma unroll 4
    for (int o = og * 64; o < og * 64 + 64; ++o) {
        const float* Pr = Pb + (size_t)o * Mk;
        yb[(size_t)o * Nq + q] = w0 * Pr[j0] + w1 * Pr[j1] + w2 * Pr[j2];
    }
}

// ---------------- generic fp32 tiled GEMM: C[b] (+)= A * Bm[b] ----------------
// A: (M, lda) row-major. Bm: (B, K, Nn). C: (B, M, Nn).
// If BN: B-operand element (k,n) is transformed max(0, v*scale[k]+bias[k]).
template <bool ACC, bool BN>
__global__ __launch_bounds__(256) void gemm_kernel(
    const float* __restrict__ A, int lda,
    const float* __restrict__ Bm,
    float* __restrict__ C,
    const float* __restrict__ scale,
    const float* __restrict__ bias,
    int M, int K, int Nn)
{
    __shared__ float As[16][65];
    __shared__ float Bs[16][64];

    const int b = blockIdx.z;
    const int m0 = blockIdx.y * 64;
    const int n0 = blockIdx.x * 64;
    const int t = threadIdx.x;
    const int tx = t & 15;   // n-groups
    const int ty = t >> 4;   // m-groups

    const float* Bb = Bm + (size_t)b * K * Nn;

    float acc[4][4] = {};

    for (int k0 = 0; k0 < K; k0 += 16) {
        // load A tile (16k x 64m)
        {
            const int ka = t & 15, ma = t >> 4;
            #pragma unroll
            for (int i = 0; i < 4; ++i)
                As[ka][ma + i * 16] = A[(size_t)(m0 + ma + i * 16) * lda + k0 + ka];
        }
        // load B tile (16k x 64n)
        {
            const int nb = t & 63, kb = t >> 6;
            #pragma unroll
            for (int i = 0; i < 4; ++i) {
                const int kk = kb + i * 4;
                float v = Bb[(size_t)(k0 + kk) * Nn + n0 + nb];
                if (BN) v = fmaxf(0.0f, v * scale[k0 + kk] + bias[k0 + kk]);
                Bs[kk][nb] = v;
            }
        }
        __syncthreads();
        #pragma unroll
        for (int k = 0; k < 16; ++k) {
            float a[4], bv[4];
            #pragma unroll
            for (int i = 0; i < 4; ++i) a[i] = As[k][ty * 4 + i];
            #pragma unroll
            for (int j = 0; j < 4; ++j) bv[j] = Bs[k][tx * 4 + j];
            #pragma unroll
            for (int i = 0; i < 4; ++i)
                #pragma unroll
                for (int j = 0; j < 4; ++j)
                    acc[i][j] += a[i] * bv[j];
        }
        __syncthreads();
    }

    float* Cb = C + (size_t)b * M * Nn;
    #pragma unroll
    for (int i = 0; i < 4; ++i) {
        #pragma unroll
        for (int j = 0; j < 4; ++j) {
            float* p = &Cb[(size_t)(m0 + ty * 4 + i) * Nn + n0 + tx * 4 + j];
            if (ACC)
                *p += acc[i][j];
            else
                *p = acc[i][j];
        }
    }
}

// ---------------- BN stats: one block per channel -> scale/bias ----------------
__global__ __launch_bounds__(256) void bnstats_kernel(
    const float* __restrict__ X,   // (B, C, Nn)
    const float* __restrict__ g,
    const float* __restrict__ beta,
    float* __restrict__ scale,
    float* __restrict__ bias,
    int C, int Nn)
{
    const int c = blockIdx.x;
    const int t = threadIdx.x;
    float s = 0.0f, sq = 0.0f;
    for (int b = 0; b < Bn; ++b) {
        const float* row = X + ((size_t)b * C + c) * Nn;
        for (int n = t * 4; n < Nn; n += 256 * 4) {
            const float4 v = *(const float4*)&row[n];
            s += v.x + v.y + v.z + v.w;
            sq += v.x * v.x + v.y * v.y + v.z * v.z + v.w * v.w;
        }
    }
    __shared__ float ss[256], ssq[256];
    ss[t] = s;
    ssq[t] = sq;
    __syncthreads();
    for (int off = 128; off > 0; off >>= 1) {
        if (t < off) {
            ss[t] += ss[t + off];
            ssq[t] += ssq[t + off];
        }
        __syncthreads();
    }
    if (t == 0) {
        const float cnt = (float)Bn * (float)Nn;
        const float mean = ss[0] / cnt;
        const float var = ssq[0] / cnt - mean * mean;
        const float rinv = rsqrtf(var + 1e-5f);
        const float sc = g[c] * rinv;
        scale[c] = sc;
        bias[c] = beta[c] - mean * sc;
    }
}

// ---------------- apply BN2+ReLU in place on output ----------------
__global__ __launch_bounds__(256) void bnapply_kernel(
    float* __restrict__ Y, const float* __restrict__ scale,
    const float* __restrict__ bias, int C, int Nn)
{
    const size_t i = ((size_t)blockIdx.x * 256 + threadIdx.x) * 4;
    const int c = (int)((i / Nn) % C);
    float4 v = *(float4*)&Y[i];
    const float sc = scale[c], bi = bias[c];
    v.x = fmaxf(0.0f, v.x * sc + bi);
    v.y = fmaxf(0.0f, v.y * sc + bi);
    v.z = fmaxf(0.0f, v.z * sc + bi);
    v.w = fmaxf(0.0f, v.w * sc + bi);
    *(float4*)&Y[i] = v;
}

extern "C" void kernel_launch(void* const* d_in, const int* in_sizes, int n_in,
                              void* d_out, int out_size, void* d_ws, size_t ws_size,
                              hipStream_t stream) {
    const float* unknown = (const float*)d_in[0];      // (B, Nq, 3)
    const float* known = (const float*)d_in[1];        // (B, Mk, 3)
    const float* unknow_feats = (const float*)d_in[2]; // (B, C1, Nq)
    const float* known_feats = (const float*)d_in[3];  // (B, C2, Mk)
    const float* W1 = (const float*)d_in[4];           // (H1, C1+C2=384)
    const float* g1 = (const float*)d_in[5];
    const float* b1 = (const float*)d_in[6];
    const float* W2 = (const float*)d_in[7];           // (H2, H1)
    const float* g2 = (const float*)d_in[8];
    const float* b2 = (const float*)d_in[9];
    float* out = (float*)d_out;                        // (B, H2, Nq)

    // workspace layout
    char* w = (char*)d_ws;
    float* P = (float*)w;                                   // B*H1*Mk
    w += (size_t)Bn * H1c * Mk * sizeof(float);
    float* y1 = (float*)w;                                  // B*H1*Nq
    w += (size_t)Bn * H1c * Nq * sizeof(float);
    int* idx = (int*)w;                                     // B*Nq*3
    w += (size_t)Bn * Nq * 3 * sizeof(int);
    float* wgt = (float*)w;                                 // B*Nq*3
    w += (size_t)Bn * Nq * 3 * sizeof(float);
    float* scale1 = (float*)w; w += H1c * sizeof(float);
    float* bias1 = (float*)w;  w += H1c * sizeof(float);
    float* scale2 = (float*)w; w += H2c * sizeof(float);
    float* bias2 = (float*)w;  w += H2c * sizeof(float);

    // 1) 3-NN
    knn_kernel<<<Bn * (Nq / 64), 256, 0, stream>>>(unknown, known, idx, wgt);

    // 2) P = W1[:, :256] @ known_feats   (B, H1, Mk)
    gemm_kernel<false, false><<<dim3(Mk / 64, H1c / 64, Bn), 256, 0, stream>>>(
        W1, C1c + C2c, known_feats, P, nullptr, nullptr, H1c, C2c, Mk);

    // 3) y1 = weighted gather of P        (B, H1, Nq)
    gather_kernel<<<Bn * (Nq / 64), 256, 0, stream>>>(P, idx, wgt, y1);

    // 4) y1 += W1[:, 256:] @ unknow_feats
    gemm_kernel<true, false><<<dim3(Nq / 64, H1c / 64, Bn), 256, 0, stream>>>(
        W1 + C2c, C1c + C2c, unknow_feats, y1, nullptr, nullptr, H1c, C1c, Nq);

    // 5) BN1 stats -> scale1/bias1
    bnstats_kernel<<<H1c, 256, 0, stream>>>(y1, g1, b1, scale1, bias1, H1c, Nq);

    // 6) out = W2 @ relu(bn1(y1))         (B, H2, Nq)
    gemm_kernel<false, true><<<dim3(Nq / 64, H2c / 64, Bn), 256, 0, stream>>>(
        W2, H1c, y1, out, scale1, bias1, H2c, H1c, Nq);

    // 7) BN2 stats -> scale2/bias2
    bnstats_kernel<<<H2c, 256, 0, stream>>>(out, g2, b2, scale2, bias2, H2c, Nq);

    // 8) out = relu(bn2(out)) in place
    bnapply_kernel<<<(Bn * H2c * Nq) / (256 * 4), 256, 0, stream>>>(out, scale2, bias2, H2c, Nq);
}

// Round 2
// 216.637 us; speedup vs baseline: 1.0981x; 1.0981x over previous
//
#include <hip/hip_runtime.h>
#include <hip/hip_bf16.h>
#include <cstdint>
#include <cstddef>

constexpr int Bn = 4;
constexpr int Nq = 8192;
constexpr int Mk = 2048;
constexpr int C1c = 128;
constexpr int C2c = 256;
constexpr int H1c = 256;
constexpr int H2c = 128;

// ---------------- 3-NN kernel: 4 threads per query ----------------
__global__ __launch_bounds__(256) void knn_kernel(
    const float* __restrict__ unknown,  // (B, Nq, 3)
    const float* __restrict__ known,    // (B, Mk, 3)
    int* __restrict__ idx_out,          // (B, Nq, 3)
    float* __restrict__ w_out)          // (B, Nq, 3)
{
    __shared__ float kx[Mk], ky[Mk], kz[Mk];
    const int b = blockIdx.x / (Nq / 64);
    const int n0 = (blockIdx.x % (Nq / 64)) * 64;
    const int t = threadIdx.x;

    const float* kb = known + (size_t)b * Mk * 3;
    for (int i = t; i < Mk; i += 256) {
        kx[i] = kb[i * 3 + 0];
        ky[i] = kb[i * 3 + 1];
        kz[i] = kb[i * 3 + 2];
    }
    __syncthreads();

    const int q = n0 + (t >> 2);
    const int s = t & 3;
    const float* u = unknown + ((size_t)b * Nq + q) * 3;
    const float ux = u[0], uy = u[1], uz = u[2];

    float d0 = 1e30f, d1 = 1e30f, d2 = 1e30f;
    int i0 = 0, i1 = 0, i2 = 0;

    auto ins = [&](float d, int i) {
        const bool c0 = d < d0, c1 = d < d1, c2 = d < d2;
        d2 = c1 ? d1 : (c2 ? d : d2);
        i2 = c1 ? i1 : (c2 ? i : i2);
        d1 = c0 ? d0 : (c1 ? d : d1);
        i1 = c0 ? i0 : (c1 ? i : i1);
        d0 = c0 ? d : d0;
        i0 = c0 ? i : i0;
    };

    const int mstart = s * (Mk / 4);
    for (int m = mstart; m < mstart + Mk / 4; ++m) {
        const float dx = ux - kx[m], dy = uy - ky[m], dz = uz - kz[m];
        ins(dx * dx + dy * dy + dz * dz, m);
    }

    #pragma unroll
    for (int off = 1; off <= 2; off <<= 1) {
        const float e0 = __shfl_xor(d0, off), e1 = __shfl_xor(d1, off), e2 = __shfl_xor(d2, off);
        const int j0 = __shfl_xor(i0, off), j1 = __shfl_xor(i1, off), j2 = __shfl_xor(i2, off);
        ins(e0, j0);
        ins(e1, j1);
        ins(e2, j2);
    }

    if (s == 0) {
        const float r0 = 1.0f / (d0 + 1e-8f);
        const float r1 = 1.0f / (d1 + 1e-8f);
        const float r2 = 1.0f / (d2 + 1e-8f);
        const float inv = 1.0f / (r0 + r1 + r2);
        const size_t base = ((size_t)b * Nq + q) * 3;
        idx_out[base + 0] = i0;
        idx_out[base + 1] = i1;
        idx_out[base + 2] = i2;
        w_out[base + 0] = r0 * inv;
        w_out[base + 1] = r1 * inv;
        w_out[base + 2] = r2 * inv;
    }
}

// ---------------- transposed-output GEMM (+ optional fused gather) ----------------
// Ct[b][m][h] = sum_k X[b][k][m] * W[h][k]   (+ gather from Pt if GATHER)
// X: (B, K, Mtot).  W: rows 0..255 (Htot=256), row stride ldw, cols [0,K).
// Ct: (B, Mtot, 256).
// Tile: 128 m x 64 h, 256 threads, 8x4 per thread.
template <bool GATHER>
__global__ __launch_bounds__(256) void gemm_t_kernel(
    const float* __restrict__ X,
    const float* __restrict__ W, int ldw, int K,
    float* __restrict__ Ct, int Mtot,
    const float* __restrict__ Pt,   // (B, Mk, 256)
    const int* __restrict__ idx,    // (B, Mtot, 3)
    const float* __restrict__ wgt)  // (B, Mtot, 3)
{
    __shared__ float Xs[16][128];
    __shared__ float Ws[16][65];

    const int b = blockIdx.z;
    const int m0 = blockIdx.x * 128;
    const int h0 = blockIdx.y * 64;
    const int t = threadIdx.x;
    const int tx = t & 15;   // h groups of 4
    const int ty = t >> 4;   // m groups of 8

    const float* Xb = X + (size_t)b * K * Mtot;

    float acc[8][4] = {};

    for (int k0 = 0; k0 < K; k0 += 16) {
        // X tile: 16k x 128m, coalesced float4 rows
        {
            const int mx = (t & 31) * 4, kx = t >> 5;
            #pragma unroll
            for (int i = 0; i < 2; ++i) {
                const float4 v = *(const float4*)&Xb[(size_t)(k0 + kx + i * 8) * Mtot + m0 + mx];
                *(float4*)&Xs[kx + i * 8][mx] = v;
            }
        }
        // W tile: 16k x 64h (strided global reads, L2-cached)
        {
            const int kw = t & 15, hw = t >> 4;
            #pragma unroll
            for (int i = 0; i < 4; ++i)
                Ws[kw][hw + i * 16] = W[(size_t)(h0 + hw + i * 16) * ldw + k0 + kw];
        }
        __syncthreads();
        #pragma unroll
        for (int k = 0; k < 16; ++k) {
            float a[8], bv[4];
            *(float4*)&a[0] = *(const float4*)&Xs[k][ty * 8];
            *(float4*)&a[4] = *(const float4*)&Xs[k][ty * 8 + 4];
            *(float4*)&bv[0] = *(const float4*)&Ws[k][tx * 4];
            #pragma unroll
            for (int i = 0; i < 8; ++i)
                #pragma unroll
                for (int j = 0; j < 4; ++j)
                    acc[i][j] += a[i] * bv[j];
        }
        __syncthreads();
    }

    if (GATHER) {
        const float* Ptb = Pt + (size_t)b * Mk * 256;
        #pragma unroll
        for (int i = 0; i < 8; ++i) {
            const int n = m0 + ty * 8 + i;
            const size_t ib = ((size_t)b * Mtot + n) * 3;
            const int j0 = idx[ib], j1 = idx[ib + 1], j2 = idx[ib + 2];
            const float w0 = wgt[ib], w1 = wgt[ib + 1], w2 = wgt[ib + 2];
            const float4 p0 = *(const float4*)&Ptb[(size_t)j0 * 256 + h0 + tx * 4];
            const float4 p1 = *(const float4*)&Ptb[(size_t)j1 * 256 + h0 + tx * 4];
            const float4 p2 = *(const float4*)&Ptb[(size_t)j2 * 256 + h0 + tx * 4];
            acc[i][0] += w0 * p0.x + w1 * p1.x + w2 * p2.x;
            acc[i][1] += w0 * p0.y + w1 * p1.y + w2 * p2.y;
            acc[i][2] += w0 * p0.z + w1 * p1.z + w2 * p2.z;
            acc[i][3] += w0 * p0.w + w1 * p1.w + w2 * p2.w;
        }
    }

    float* Cb = Ct + ((size_t)b * Mtot + m0) * 256;
    #pragma unroll
    for (int i = 0; i < 8; ++i) {
        float4 v;
        v.x = acc[i][0]; v.y = acc[i][1]; v.z = acc[i][2]; v.w = acc[i][3];
        *(float4*)&Cb[(size_t)(ty * 8 + i) * 256 + h0 + tx * 4] = v;
    }
}

// ---------------- BN1 stats over y1t (B*Nq, 256): stage 1 partials ----------------
__global__ __launch_bounds__(256) void bn1_partial_kernel(
    const float* __restrict__ Y,   // (R, 256)
    float* __restrict__ partS,     // (nblk, 256)
    float* __restrict__ partQ,
    int rows_per_blk)
{
    const int blk = blockIdx.x;
    const int t = threadIdx.x;
    const int ch4 = (t & 63) * 4;
    const int ro = t >> 6;
    const size_t row0 = (size_t)blk * rows_per_blk;

    float4 s = {0, 0, 0, 0}, q = {0, 0, 0, 0};
    for (int r = ro; r < rows_per_blk; r += 4) {
        const float4 v = *(const float4*)&Y[(row0 + r) * 256 + ch4];
        s.x += v.x; s.y += v.y; s.z += v.z; s.w += v.w;
        q.x += v.x * v.x; q.y += v.y * v.y; q.z += v.z * v.z; q.w += v.w * v.w;
    }
    __shared__ float4 ss[256], sq[256];
    ss[t] = s;
    sq[t] = q;
    __syncthreads();
    if (t < 64) {
        float4 a = ss[t], b4 = ss[t + 64], c4 = ss[t + 128], d4 = ss[t + 192];
        s.x = a.x + b4.x + c4.x + d4.x;
        s.y = a.y + b4.y + c4.y + d4.y;
        s.z = a.z + b4.z + c4.z + d4.z;
        s.w = a.w + b4.w + c4.w + d4.w;
        a = sq[t]; b4 = sq[t + 64]; c4 = sq[t + 128]; d4 = sq[t + 192];
        q.x = a.x + b4.x + c4.x + d4.x;
        q.y = a.y + b4.y + c4.y + d4.y;
        q.z = a.z + b4.z + c4.z + d4.z;
        q.w = a.w + b4.w + c4.w + d4.w;
        *(float4*)&partS[(size_t)blk * 256 + t * 4] = s;
        *(float4*)&partQ[(size_t)blk * 256 + t * 4] = q;
    }
}

__global__ __launch_bounds__(256) void bn1_finalize_kernel(
    const float* __restrict__ partS, const float* __restrict__ partQ,
    const float* __restrict__ g, const float* __restrict__ beta,
    float* __restrict__ scale, float* __restrict__ bias, int nblk, float cnt)
{
    const int c = threadIdx.x;  // 256 channels
    float s = 0.0f, q = 0.0f;
    for (int i = 0; i < nblk; ++i) {
        s += partS[(size_t)i * 256 + c];
        q += partQ[(size_t)i * 256 + c];
    }
    const float mean = s / cnt;
    const float var = q / cnt - mean * mean;
    const float r = rsqrtf(var + 1e-5f);
    const float sc = g[c] * r;
    scale[c] = sc;
    bias[c] = beta[c] - mean * sc;
}

// ---------------- GEMM2: out[b][o][n] = sum_h W2[o][h]*relu(bn(y1t[b][n][h])) ----------------
// Tile: 64 o x 128 n, 256 threads, 4x8 per thread.
__global__ __launch_bounds__(256) void gemm2_kernel(
    const float* __restrict__ W2,     // (128, 256)
    const float* __restrict__ Y,      // (B, Nq, 256)
    const float* __restrict__ scale,  // (256)
    const float* __restrict__ bias,   // (256)
    float* __restrict__ out)          // (B, 128, Nq)
{
    __shared__ float As[16][65];   // k x o
    __shared__ float Bs[16][128];  // k x n
    __shared__ float sc_s[256], bi_s[256];

    const int b = blockIdx.z;
    const int o0 = blockIdx.y * 64;
    const int n0 = blockIdx.x * 128;
    const int t = threadIdx.x;
    const int tn = t & 15;   // n groups
    const int to = t >> 4;   // o groups of 4

    sc_s[t] = scale[t];
    bi_s[t] = bias[t];

    const float* Yb = Y + (size_t)b * Nq * 256;
    float acc[4][8] = {};

    for (int k0 = 0; k0 < 256; k0 += 16) {
        // A tile: W2[o][k] -> As[k][o]
        {
            const int ka = t & 15, oa = t >> 4;
            #pragma unroll
            for (int i = 0; i < 4; ++i)
                As[ka][oa + i * 16] = W2[(size_t)(o0 + oa + i * 16) * 256 + k0 + ka];
        }
        __syncthreads();  // also covers sc_s/bi_s on first iteration
        // B tile: Y[n][k] -> Bs[k][n] with BN+ReLU
        {
            const int nb = t >> 1, kb = (t & 1) * 8;
            const float4 va = *(const float4*)&Yb[(size_t)(n0 + nb) * 256 + k0 + kb];
            const float4 vb = *(const float4*)&Yb[(size_t)(n0 + nb) * 256 + k0 + kb + 4];
            const float* sc = &sc_s[k0 + kb];
            const float* bi = &bi_s[k0 + kb];
            Bs[kb + 0][nb] = fmaxf(0.0f, va.x * sc[0] + bi[0]);
            Bs[kb + 1][nb] = fmaxf(0.0f, va.y * sc[1] + bi[1]);
            Bs[kb + 2][nb] = fmaxf(0.0f, va.z * sc[2] + bi[2]);
            Bs[kb + 3][nb] = fmaxf(0.0f, va.w * sc[3] + bi[3]);
            Bs[kb + 4][nb] = fmaxf(0.0f, vb.x * sc[4] + bi[4]);
            Bs[kb + 5][nb] = fmaxf(0.0f, vb.y * sc[5] + bi[5]);
            Bs[kb + 6][nb] = fmaxf(0.0f, vb.z * sc[6] + bi[6]);
            Bs[kb + 7][nb] = fmaxf(0.0f, vb.w * sc[7] + bi[7]);
        }
        __syncthreads();
        #pragma unroll
        for (int k = 0; k < 16; ++k) {
            float a[4], bv[8];
            *(float4*)&a[0] = *(const float4*)&As[k][to * 4];
            *(float4*)&bv[0] = *(const float4*)&Bs[k][tn * 4];
            *(float4*)&bv[4] = *(const float4*)&Bs[k][64 + tn * 4];
            #pragma unroll
            for (int i = 0; i < 4; ++i)
                #pragma unroll
                for (int j = 0; j < 8; ++j)
                    acc[i][j] += a[i] * bv[j];
        }
        __syncthreads();
    }

    float* ob = out + ((size_t)b * H2c + o0) * Nq;
    #pragma unroll
    for (int i = 0; i < 4; ++i) {
        float4 v0, v1;
        v0.x = acc[i][0]; v0.y = acc[i][1]; v0.z = acc[i][2]; v0.w = acc[i][3];
        v1.x = acc[i][4]; v1.y = acc[i][5]; v1.z = acc[i][6]; v1.w = acc[i][7];
        *(float4*)&ob[(size_t)(to * 4 + i) * Nq + n0 + tn * 4] = v0;
        *(float4*)&ob[(size_t)(to * 4 + i) * Nq + n0 + 64 + tn * 4] = v1;
    }
}

// ---------------- BN stats for channel-major (B, C, Nn) ----------------
__global__ __launch_bounds__(256) void bnstats_kernel(
    const float* __restrict__ X,
    const float* __restrict__ g,
    const float* __restrict__ beta,
    float* __restrict__ scale,
    float* __restrict__ bias,
    int C, int Nn)
{
    const int c = blockIdx.x;
    const int t = threadIdx.x;
    float s = 0.0f, sq = 0.0f;
    for (int b = 0; b < Bn; ++b) {
        const float* row = X + ((size_t)b * C + c) * Nn;
        for (int n = t * 4; n < Nn; n += 256 * 4) {
            const float4 v = *(const float4*)&row[n];
            s += v.x + v.y + v.z + v.w;
            sq += v.x * v.x + v.y * v.y + v.z * v.z + v.w * v.w;
        }
    }
    __shared__ float ss[256], ssq[256];
    ss[t] = s;
    ssq[t] = sq;
    __syncthreads();
    for (int off = 128; off > 0; off >>= 1) {
        if (t < off) {
            ss[t] += ss[t + off];
            ssq[t] += ssq[t + off];
        }
        __syncthreads();
    }
    if (t == 0) {
        const float cnt = (float)Bn * (float)Nn;
        const float mean = ss[0] / cnt;
        const float var = ssq[0] / cnt - mean * mean;
        const float rinv = rsqrtf(var + 1e-5f);
        const float sc = g[c] * rinv;
        scale[c] = sc;
        bias[c] = beta[c] - mean * sc;
    }
}

// ---------------- apply BN2+ReLU in place ----------------
__global__ __launch_bounds__(256) void bnapply_kernel(
    float* __restrict__ Y, const float* __restrict__ scale,
    const float* __restrict__ bias, int C, int Nn)
{
    const size_t i = ((size_t)blockIdx.x * 256 + threadIdx.x) * 4;
    const int c = (int)((i / Nn) % C);
    float4 v = *(float4*)&Y[i];
    const float sc = scale[c], bi = bias[c];
    v.x = fmaxf(0.0f, v.x * sc + bi);
    v.y = fmaxf(0.0f, v.y * sc + bi);
    v.z = fmaxf(0.0f, v.z * sc + bi);
    v.w = fmaxf(0.0f, v.w * sc + bi);
    *(float4*)&Y[i] = v;
}

extern "C" void kernel_launch(void* const* d_in, const int* in_sizes, int n_in,
                              void* d_out, int out_size, void* d_ws, size_t ws_size,
                              hipStream_t stream) {
    const float* unknown = (const float*)d_in[0];      // (B, Nq, 3)
    const float* known = (const float*)d_in[1];        // (B, Mk, 3)
    const float* unknow_feats = (const float*)d_in[2]; // (B, C1, Nq)
    const float* known_feats = (const float*)d_in[3];  // (B, C2, Mk)
    const float* W1 = (const float*)d_in[4];           // (H1, 384)
    const float* g1 = (const float*)d_in[5];
    const float* b1 = (const float*)d_in[6];
    const float* W2 = (const float*)d_in[7];           // (H2, H1)
    const float* g2 = (const float*)d_in[8];
    const float* b2 = (const float*)d_in[9];
    float* out = (float*)d_out;                        // (B, H2, Nq)

    // workspace layout
    char* w = (char*)d_ws;
    float* Pt = (float*)w;                                  // B*Mk*H1
    w += (size_t)Bn * Mk * H1c * sizeof(float);
    float* y1t = (float*)w;                                 // B*Nq*H1
    w += (size_t)Bn * Nq * H1c * sizeof(float);
    int* idx = (int*)w;                                     // B*Nq*3
    w += (size_t)Bn * Nq * 3 * sizeof(int);
    float* wgt = (float*)w;                                 // B*Nq*3
    w += (size_t)Bn * Nq * 3 * sizeof(float);
    constexpr int NBLK1 = 128;
    float* partS = (float*)w; w += (size_t)NBLK1 * H1c * sizeof(float);
    float* partQ = (float*)w; w += (size_t)NBLK1 * H1c * sizeof(float);
    float* scale1 = (float*)w; w += H1c * sizeof(float);
    float* bias1 = (float*)w;  w += H1c * sizeof(float);
    float* scale2 = (float*)w; w += H2c * sizeof(float);
    float* bias2 = (float*)w;  w += H2c * sizeof(float);

    // 1) 3-NN
    knn_kernel<<<Bn * (Nq / 64), 256, 0, stream>>>(unknown, known, idx, wgt);

    // 2) Pt[b][m][h] = sum_c kf[b][c][m] * W1[h][c]
    gemm_t_kernel<false><<<dim3(Mk / 128, H1c / 64, Bn), 256, 0, stream>>>(
        known_feats, W1, C1c + C2c, C2c, Pt, Mk, nullptr, nullptr, nullptr);

    // 3) y1t[b][n][h] = sum_c uf[b][c][n] * W1[h][256+c] + gather(Pt, idx, wgt)
    gemm_t_kernel<true><<<dim3(Nq / 128, H1c / 64, Bn), 256, 0, stream>>>(
        unknow_feats, W1 + C2c, C1c + C2c, C1c, y1t, Nq, Pt, idx, wgt);

    // 4) BN1 stats
    bn1_partial_kernel<<<NBLK1, 256, 0, stream>>>(y1t, partS, partQ, (Bn * Nq) / NBLK1);
    bn1_finalize_kernel<<<1, 256, 0, stream>>>(partS, partQ, g1, b1, scale1, bias1,
                                               NBLK1, (float)(Bn * Nq));

    // 5) out = W2 @ relu(bn1(y1t))
    gemm2_kernel<<<dim3(Nq / 128, H2c / 64, Bn), 256, 0, stream>>>(
        W2, y1t, scale1, bias1, out);

    // 6) BN2 stats + apply
    bnstats_kernel<<<H2c, 256, 0, stream>>>(out, g2, b2, scale2, bias2, H2c, Nq);
    bnapply_kernel<<<(Bn * H2c * Nq) / (256 * 4), 256, 0, stream>>>(out, scale2, bias2, H2c, Nq);
}

// Round 4
// 154.455 us; speedup vs baseline: 1.5401x; 1.4026x over previous
//
#include <hip/hip_runtime.h>
#include <hip/hip_bf16.h>
#include <cstdint>
#include <cstddef>

typedef unsigned short u16;
typedef __attribute__((ext_vector_type(8))) short bf16x8;
typedef __attribute__((ext_vector_type(4))) float f32x4;

constexpr int Bn = 4;
constexpr int Nq = 8192;
constexpr int Mk = 2048;
constexpr int C1c = 128;
constexpr int C2c = 256;
constexpr int H1c = 256;
constexpr int H2c = 128;

__device__ __forceinline__ float bf2f(u16 u) {
    union { uint32_t i; float f; } v;
    v.i = (uint32_t)u << 16;
    return v.f;
}
__device__ __forceinline__ u16 f2bf(float f) {
    const uint32_t x = __float_as_uint(f);
    return (u16)((x + 0x7FFFu + ((x >> 16) & 1u)) >> 16);
}

// ---------------- 3-NN: exact f32 compare, 8 lanes/query, conflict-free LDS ----------------
__global__ __launch_bounds__(256) void knn_kernel(
    const float* __restrict__ unknown,  // (B, Nq, 3)
    const float* __restrict__ known,    // (B, Mk, 3)
    int* __restrict__ idx_out,          // (B, Nq, 3)
    float* __restrict__ w_out)          // (B, Nq, 3)
{
    __shared__ float4 kp[Mk];  // (x, y, z, |k|^2), 32 KB
    const int b = blockIdx.x / (Nq / 32);
    const int n0 = (blockIdx.x % (Nq / 32)) * 32;
    const int t = threadIdx.x;

    const float* kb = known + (size_t)b * Mk * 3;
    for (int i = t; i < Mk; i += 256) {
        const float x = kb[i * 3 + 0], y = kb[i * 3 + 1], z = kb[i * 3 + 2];
        kp[i] = make_float4(x, y, z, fmaf(x, x, fmaf(y, y, z * z)));
    }
    __syncthreads();

    const int q = n0 + (t >> 3);
    const int s = t & 7;
    const float* u = unknown + ((size_t)b * Nq + q) * 3;
    const float ux = u[0], uy = u[1], uz = u[2];
    const float nux = -2.0f * ux, nuy = -2.0f * uy, nuz = -2.0f * uz;
    const float uu = fmaf(ux, ux, fmaf(uy, uy, uz * uz));

    // track d' = |k|^2 - 2 u.k  (ordering identical to true squared distance)
    float d0 = 1e30f, d1 = 1e30f, d2 = 1e30f;
    int i0 = 0, i1 = 0, i2 = 0;

    auto ins = [&](float d, int i) {
        const bool c0 = d < d0, c1 = d < d1, c2 = d < d2;
        d2 = c1 ? d1 : (c2 ? d : d2);
        i2 = c1 ? i1 : (c2 ? i : i2);
        d1 = c0 ? d0 : (c1 ? d : d1);
        i1 = c0 ? i0 : (c1 ? i : i1);
        d0 = c0 ? d : d0;
        i0 = c0 ? i : i0;
    };

    for (int it = 0; it < Mk / 8; ++it) {
        const int m = it * 8 + s;  // 8 consecutive float4 slots per step: conflict-free
        const float4 p = kp[m];
        const float d = fmaf(nux, p.x, fmaf(nuy, p.y, fmaf(nuz, p.z, p.w)));
        ins(d, m);
    }

    // butterfly merge over 8 slice-lanes (exact compares)
    #pragma unroll
    for (int off = 1; off <= 4; off <<= 1) {
        const float e0 = __shfl_xor(d0, off), e1 = __shfl_xor(d1, off), e2 = __shfl_xor(d2, off);
        const int j0 = __shfl_xor(i0, off), j1 = __shfl_xor(i1, off), j2 = __shfl_xor(i2, off);
        ins(e0, j0);
        ins(e1, j1);
        ins(e2, j2);
    }

    if (s == 0) {
        const float f0 = d0 + uu, f1 = d1 + uu, f2 = d2 + uu;  // true squared distances
        const float r0 = 1.0f / (f0 + 1e-8f);
        const float r1 = 1.0f / (f1 + 1e-8f);
        const float r2 = 1.0f / (f2 + 1e-8f);
        const float inv = 1.0f / (r0 + r1 + r2);
        const size_t base = ((size_t)b * Nq + q) * 3;
        idx_out[base + 0] = i0;
        idx_out[base + 1] = i1;
        idx_out[base + 2] = i2;
        w_out[base + 0] = r0 * inv;
        w_out[base + 1] = r1 * inv;
        w_out[base + 2] = r2 * inv;
    }
}

// ---------------- transpose + f32->bf16: X (B,C,M) -> Y (B,M,C) ----------------
__global__ __launch_bounds__(256) void transpose_cvt(
    const float* __restrict__ X, u16* __restrict__ Y, int C, int M)
{
    __shared__ float T[64][65];
    const int b = blockIdx.z;
    const int m0 = blockIdx.x * 64, c0 = blockIdx.y * 64;
    const int t = threadIdx.x;
    const float* Xb = X + (size_t)b * C * M;
    u16* Yb = Y + (size_t)b * M * C;

    const int m4 = (t & 15) * 4, cr = t >> 4;
    #pragma unroll
    for (int i = 0; i < 4; ++i) {
        const float4 v = *(const float4*)&Xb[(size_t)(c0 + cr + i * 16) * M + m0 + m4];
        T[cr + i * 16][m4 + 0] = v.x;
        T[cr + i * 16][m4 + 1] = v.y;
        T[cr + i * 16][m4 + 2] = v.z;
        T[cr + i * 16][m4 + 3] = v.w;
    }
    __syncthreads();
    const int c4 = (t & 15) * 4, mr = t >> 4;
    #pragma unroll
    for (int i = 0; i < 4; ++i) {
        const int m = mr + i * 16;
        ushort4 o;
        o.x = f2bf(T[c4 + 0][m]);
        o.y = f2bf(T[c4 + 1][m]);
        o.z = f2bf(T[c4 + 2][m]);
        o.w = f2bf(T[c4 + 3][m]);
        *(ushort4*)&Yb[(size_t)(m0 + m) * C + c0 + c4] = o;
    }
}

// ---------------- flat f32->bf16 ----------------
__global__ __launch_bounds__(256) void cvt_flat(
    const float* __restrict__ X, u16* __restrict__ Y, int n4)
{
    const int i = blockIdx.x * 256 + threadIdx.x;
    if (i < n4) {
        const float4 v = *(const float4*)&X[(size_t)i * 4];
        ushort4 o;
        o.x = f2bf(v.x); o.y = f2bf(v.y); o.z = f2bf(v.z); o.w = f2bf(v.w);
        *(ushort4*)&Y[(size_t)i * 4] = o;
    }
}

// ---------------- bf16 MFMA bt-GEMM: C(M,N) = A(M,K) * Bt(N,K)^T ----------------
// 128x128 tile, BK=32, 4 waves (2x2 of 64x64), mfma_f32_16x16x32_bf16.
// A-op lane: row=l&15, k=(l>>4)*8+i ; B-op lane: col=l&15, k=(l>>4)*8+i ;
// D: col=l&15, row=(l>>4)*4+reg  [m89-verified].
template <bool GATHER, bool OUT_BF16>
__global__ __launch_bounds__(256) void mfma_gemm(
    const u16* __restrict__ A, int lda, size_t sA,
    const u16* __restrict__ Bt, int ldb, size_t sB,
    void* __restrict__ Cout, int ldc, size_t sC,
    int nK,
    const u16* __restrict__ Ptb,
    const int* __restrict__ idx, const float* __restrict__ wgt, int nrows)
{
    __shared__ u16 As[4096];  // [128 rows][32 k]
    __shared__ u16 Bs[4096];

    const int b = blockIdx.z;
    const int m0 = blockIdx.x * 128, n0 = blockIdx.y * 128;
    const int t = threadIdx.x;
    const int l = t & 63, wv = t >> 6;
    const int wr = wv >> 1, wc = wv & 1;

    const u16* Ab = A + (size_t)b * sA;
    const u16* Btb = Bt + (size_t)b * sB;

    const int i0 = t, i1 = t + 256;
    const int rA0 = i0 >> 2, rA1 = i1 >> 2;
    const int ko = (t & 3) * 8;

    f32x4 acc[4][4];
    const f32x4 z = {0.0f, 0.0f, 0.0f, 0.0f};
    #pragma unroll
    for (int i = 0; i < 4; ++i)
        #pragma unroll
        for (int j = 0; j < 4; ++j) acc[i][j] = z;

    uint4 a0 = *(const uint4*)&Ab[(size_t)(m0 + rA0) * lda + ko];
    uint4 a1 = *(const uint4*)&Ab[(size_t)(m0 + rA1) * lda + ko];
    uint4 b0 = *(const uint4*)&Btb[(size_t)(n0 + rA0) * ldb + ko];
    uint4 b1 = *(const uint4*)&Btb[(size_t)(n0 + rA1) * ldb + ko];

    for (int kt = 0; kt < nK; ++kt) {
        *(uint4*)&As[i0 * 8] = a0;
        *(uint4*)&As[i1 * 8] = a1;
        *(uint4*)&Bs[i0 * 8] = b0;
        *(uint4*)&Bs[i1 * 8] = b1;
        __syncthreads();
        if (kt + 1 < nK) {
            const int k0 = (kt + 1) * 32;
            a0 = *(const uint4*)&Ab[(size_t)(m0 + rA0) * lda + k0 + ko];
            a1 = *(const uint4*)&Ab[(size_t)(m0 + rA1) * lda + k0 + ko];
            b0 = *(const uint4*)&Btb[(size_t)(n0 + rA0) * ldb + k0 + ko];
            b1 = *(const uint4*)&Btb[(size_t)(n0 + rA1) * ldb + k0 + ko];
        }
        bf16x8 af[4], bf[4];
        #pragma unroll
        for (int f = 0; f < 4; ++f) {
            af[f] = *(const bf16x8*)&As[(wr * 64 + f * 16 + (l & 15)) * 32 + (l >> 4) * 8];
            bf[f] = *(const bf16x8*)&Bs[(wc * 64 + f * 16 + (l & 15)) * 32 + (l >> 4) * 8];
        }
        #pragma unroll
        for (int i = 0; i < 4; ++i)
            #pragma unroll
            for (int j = 0; j < 4; ++j)
                acc[i][j] = __builtin_amdgcn_mfma_f32_16x16x32_bf16(af[i], bf[j], acc[i][j], 0, 0, 0);
        __syncthreads();
    }

    const int cb = l & 15;
    const int rg = (l >> 4) * 4;
    #pragma unroll
    for (int i = 0; i < 4; ++i) {
        #pragma unroll
        for (int r = 0; r < 4; ++r) {
            const int R = m0 + wr * 64 + i * 16 + rg + r;
            const u16 *P0 = nullptr, *P1 = nullptr, *P2 = nullptr;
            float w0 = 0.0f, w1 = 0.0f, w2 = 0.0f;
            if (GATHER) {
                const size_t ib = ((size_t)b * nrows + R) * 3;
                const int j0 = idx[ib], j1 = idx[ib + 1], j2 = idx[ib + 2];
                w0 = wgt[ib];
                w1 = wgt[ib + 1];
                w2 = wgt[ib + 2];
                const u16* Pb = Ptb + (size_t)b * Mk * 256;
                P0 = Pb + (size_t)j0 * 256;
                P1 = Pb + (size_t)j1 * 256;
                P2 = Pb + (size_t)j2 * 256;
            }
            #pragma unroll
            for (int j = 0; j < 4; ++j) {
                const int Cc = n0 + wc * 64 + j * 16 + cb;
                float v = acc[i][j][r];
                if (GATHER)
                    v += w0 * bf2f(P0[Cc]) + w1 * bf2f(P1[Cc]) + w2 * bf2f(P2[Cc]);
                if (OUT_BF16)
                    ((u16*)Cout)[(size_t)b * sC + (size_t)R * ldc + Cc] = f2bf(v);
                else
                    ((float*)Cout)[(size_t)b * sC + (size_t)R * ldc + Cc] = v;
            }
        }
    }
}

// ---------------- BN1 partial stats over y1b (32768, 256) bf16 ----------------
__global__ __launch_bounds__(256) void bn1_partial(
    const u16* __restrict__ Y, float* __restrict__ partS, float* __restrict__ partQ, int rpb)
{
    const int blk = blockIdx.x, t = threadIdx.x;
    const int co = (t & 31) * 8;
    const int ro = t >> 5;
    float s[8] = {0, 0, 0, 0, 0, 0, 0, 0}, q[8] = {0, 0, 0, 0, 0, 0, 0, 0};
    const size_t row0 = (size_t)blk * rpb;
    for (int r = ro; r < rpb; r += 8) {
        const uint4 v = *(const uint4*)&Y[(row0 + r) * 256 + co];
        const u16* pv = (const u16*)&v;
        #pragma unroll
        for (int j = 0; j < 8; ++j) {
            const float f = bf2f(pv[j]);
            s[j] += f;
            q[j] += f * f;
        }
    }
    __shared__ float red[8][256];
    #pragma unroll
    for (int j = 0; j < 8; ++j) red[ro][co + j] = s[j];
    __syncthreads();
    {
        float a = 0;
        #pragma unroll
        for (int g = 0; g < 8; ++g) a += red[g][t];
        partS[(size_t)blk * 256 + t] = a;
    }
    __syncthreads();
    #pragma unroll
    for (int j = 0; j < 8; ++j) red[ro][co + j] = q[j];
    __syncthreads();
    {
        float a = 0;
        #pragma unroll
        for (int g = 0; g < 8; ++g) a += red[g][t];
        partQ[(size_t)blk * 256 + t] = a;
    }
}

__global__ __launch_bounds__(256) void bn1_finalize(
    const float* __restrict__ partS, const float* __restrict__ partQ,
    const float* __restrict__ g, const float* __restrict__ beta,
    float* __restrict__ scale, float* __restrict__ bias, int nblk, float cnt)
{
    const int c = threadIdx.x;
    float s = 0.0f, q = 0.0f;
    for (int i = 0; i < nblk; ++i) {
        s += partS[(size_t)i * 256 + c];
        q += partQ[(size_t)i * 256 + c];
    }
    const float mean = s / cnt;
    const float var = q / cnt - mean * mean;
    const float r = rsqrtf(var + 1e-5f);
    const float sc = g[c] * r;
    scale[c] = sc;
    bias[c] = beta[c] - mean * sc;
}

// ---------------- BN1 apply + ReLU: y1b -> ytb (bf16) ----------------
__global__ __launch_bounds__(256) void bn1_apply(
    const u16* __restrict__ Y, u16* __restrict__ Yt,
    const float* __restrict__ scale, const float* __restrict__ bias)
{
    __shared__ float scs[256], bis[256];
    const int t = threadIdx.x;
    scs[t] = scale[t];
    bis[t] = bias[t];
    __syncthreads();
    const size_t i = ((size_t)blockIdx.x * 256 + t) * 8;
    const int c = (int)(i & 255);
    const uint4 v = *(const uint4*)&Y[i];
    const u16* pv = (const u16*)&v;
    u16 o[8];
    #pragma unroll
    for (int j = 0; j < 8; ++j)
        o[j] = f2bf(fmaxf(0.0f, bf2f(pv[j]) * scs[c + j] + bis[c + j]));
    *(uint4*)&Yt[i] = *(const uint4*)o;
}

// ---------------- BN2 stats (f32 channel-major) ----------------
__global__ __launch_bounds__(256) void bnstats_kernel(
    const float* __restrict__ X, const float* __restrict__ g,
    const float* __restrict__ beta, float* __restrict__ scale,
    float* __restrict__ bias, int C, int Nn)
{
    const int c = blockIdx.x;
    const int t = threadIdx.x;
    float s = 0.0f, sq = 0.0f;
    for (int b = 0; b < Bn; ++b) {
        const float* row = X + ((size_t)b * C + c) * Nn;
        for (int n = t * 4; n < Nn; n += 256 * 4) {
            const float4 v = *(const float4*)&row[n];
            s += v.x + v.y + v.z + v.w;
            sq += v.x * v.x + v.y * v.y + v.z * v.z + v.w * v.w;
        }
    }
    __shared__ float ss[256], ssq[256];
    ss[t] = s;
    ssq[t] = sq;
    __syncthreads();
    for (int off = 128; off > 0; off >>= 1) {
        if (t < off) {
            ss[t] += ss[t + off];
            ssq[t] += ssq[t + off];
        }
        __syncthreads();
    }
    if (t == 0) {
        const float cnt = (float)Bn * (float)Nn;
        const float mean = ss[0] / cnt;
        const float var = ssq[0] / cnt - mean * mean;
        const float rinv = rsqrtf(var + 1e-5f);
        const float sc = g[c] * rinv;
        scale[c] = sc;
        bias[c] = beta[c] - mean * sc;
    }
}

__global__ __launch_bounds__(256) void bnapply_kernel(
    float* __restrict__ Y, const float* __restrict__ scale,
    const float* __restrict__ bias, int C, int Nn)
{
    const size_t i = ((size_t)blockIdx.x * 256 + threadIdx.x) * 4;
    const int c = (int)((i / Nn) % C);
    float4 v = *(float4*)&Y[i];
    const float sc = scale[c], bi = bias[c];
    v.x = fmaxf(0.0f, v.x * sc + bi);
    v.y = fmaxf(0.0f, v.y * sc + bi);
    v.z = fmaxf(0.0f, v.z * sc + bi);
    v.w = fmaxf(0.0f, v.w * sc + bi);
    *(float4*)&Y[i] = v;
}

extern "C" void kernel_launch(void* const* d_in, const int* in_sizes, int n_in,
                              void* d_out, int out_size, void* d_ws, size_t ws_size,
                              hipStream_t stream) {
    const float* unknown = (const float*)d_in[0];      // (B, Nq, 3)
    const float* known = (const float*)d_in[1];        // (B, Mk, 3)
    const float* unknow_feats = (const float*)d_in[2]; // (B, C1, Nq)
    const float* known_feats = (const float*)d_in[3];  // (B, C2, Mk)
    const float* W1 = (const float*)d_in[4];           // (256, 384)
    const float* g1 = (const float*)d_in[5];
    const float* b1 = (const float*)d_in[6];
    const float* W2 = (const float*)d_in[7];           // (128, 256)
    const float* g2 = (const float*)d_in[8];
    const float* b2 = (const float*)d_in[9];
    float* out = (float*)d_out;                        // (B, 128, Nq)

    // workspace layout (all 16B aligned)
    char* w = (char*)d_ws;
    u16* KFt = (u16*)w; w += (size_t)Bn * Mk * C2c * 2;        // (B, 2048, 256) bf16
    u16* UFt = (u16*)w; w += (size_t)Bn * Nq * C1c * 2;        // (B, 8192, 128) bf16
    u16* W1b = (u16*)w; w += (size_t)H1c * 384 * 2;            // (256, 384) bf16
    u16* W2b = (u16*)w; w += (size_t)H2c * H1c * 2;            // (128, 256) bf16
    u16* Ptb = (u16*)w; w += (size_t)Bn * Mk * H1c * 2;        // (B, 2048, 256) bf16
    u16* y1b = (u16*)w; w += (size_t)Bn * Nq * H1c * 2;        // (B, 8192, 256) bf16
    u16* ytb = (u16*)w; w += (size_t)Bn * Nq * H1c * 2;        // (B, 8192, 256) bf16
    int* idx = (int*)w; w += (size_t)Bn * Nq * 3 * 4;
    float* wgt = (float*)w; w += (size_t)Bn * Nq * 3 * 4;
    constexpr int NBLK1 = 128;
    float* partS = (float*)w; w += (size_t)NBLK1 * H1c * 4;
    float* partQ = (float*)w; w += (size_t)NBLK1 * H1c * 4;
    float* scale1 = (float*)w; w += 1024;
    float* bias1 = (float*)w; w += 1024;
    float* scale2 = (float*)w; w += 1024;
    float* bias2 = (float*)w; w += 1024;

    // 0) convert weights to bf16
    cvt_flat<<<(H1c * 384 / 4 + 255) / 256, 256, 0, stream>>>(W1, W1b, H1c * 384 / 4);
    cvt_flat<<<(H2c * H1c / 4 + 255) / 256, 256, 0, stream>>>(W2, W2b, H2c * H1c / 4);

    // 1) transpose+convert feats
    transpose_cvt<<<dim3(Mk / 64, C2c / 64, Bn), 256, 0, stream>>>(known_feats, KFt, C2c, Mk);
    transpose_cvt<<<dim3(Nq / 64, C1c / 64, Bn), 256, 0, stream>>>(unknow_feats, UFt, C1c, Nq);

    // 2) 3-NN (exact)
    knn_kernel<<<Bn * (Nq / 32), 256, 0, stream>>>(unknown, known, idx, wgt);

    // 3) Ptb(b,m,h) = KFt(b,m,:) @ W1[:, :256]^T
    mfma_gemm<false, true><<<dim3(Mk / 128, H1c / 128, Bn), 256, 0, stream>>>(
        KFt, C2c, (size_t)Mk * C2c,
        W1b, 384, 0,
        Ptb, H1c, (size_t)Mk * H1c,
        C2c / 32, nullptr, nullptr, nullptr, 0);

    // 4) y1b(b,n,h) = UFt(b,n,:) @ W1[:, 256:]^T + gather(Ptb)
    mfma_gemm<true, true><<<dim3(Nq / 128, H1c / 128, Bn), 256, 0, stream>>>(
        UFt, C1c, (size_t)Nq * C1c,
        W1b + C2c, 384, 0,
        y1b, H1c, (size_t)Nq * H1c,
        C1c / 32, Ptb, idx, wgt, Nq);

    // 5) BN1 stats + apply
    bn1_partial<<<NBLK1, 256, 0, stream>>>(y1b, partS, partQ, (Bn * Nq) / NBLK1);
    bn1_finalize<<<1, 256, 0, stream>>>(partS, partQ, g1, b1, scale1, bias1, NBLK1,
                                        (float)(Bn * Nq));
    bn1_apply<<<(Bn * Nq * H1c / 8) / 256, 256, 0, stream>>>(y1b, ytb, scale1, bias1);

    // 6) out(b,o,n) = W2(o,:) @ ytb(b,n,:)^T
    mfma_gemm<false, false><<<dim3(1, Nq / 128, Bn), 256, 0, stream>>>(
        W2b, H1c, 0,
        ytb, H1c, (size_t)Nq * H1c,
        out, Nq, (size_t)H2c * Nq,
        H1c / 32, nullptr, nullptr, nullptr, 0);

    // 7) BN2 stats + apply (f32)
    bnstats_kernel<<<H2c, 256, 0, stream>>>(out, g2, b2, scale2, bias2, H2c, Nq);
    bnapply_kernel<<<(Bn * H2c * Nq) / (256 * 4), 256, 0, stream>>>(out, scale2, bias2, H2c, Nq);
}

// Round 5
// 109.305 us; speedup vs baseline: 2.1763x; 1.4131x over previous
//
#include <hip/hip_runtime.h>
#include <hip/hip_bf16.h>
#include <cstdint>
#include <cstddef>

typedef unsigned short u16;
typedef __attribute__((ext_vector_type(8))) short bf16x8;
typedef __attribute__((ext_vector_type(4))) float f32x4;

constexpr int Bn = 4;
constexpr int Nq = 8192;
constexpr int Mk = 2048;
constexpr int C1c = 128;
constexpr int C2c = 256;
constexpr int H1c = 256;
constexpr int H2c = 128;

__device__ __forceinline__ float bf2f(u16 u) {
    union { uint32_t i; float f; } v;
    v.i = (uint32_t)u << 16;
    return v.f;
}
__device__ __forceinline__ u16 f2bf(float f) {
    const uint32_t x = __float_as_uint(f);
    return (u16)((x + 0x7FFFu + ((x >> 16) & 1u)) >> 16);
}

// ================= fused prep (cvt W1, cvt W2, transpose KF, transpose UF) + knn =================
// block ranges: [0,96) cvt W1 | [96,128) cvt W2 | [128,640) KF | [640,1664) UF | [1664,2688) knn
__global__ __launch_bounds__(256) void prep_knn_kernel(
    const float* __restrict__ W1, const float* __restrict__ W2,
    u16* __restrict__ W1b, u16* __restrict__ W2b,
    const float* __restrict__ KF, u16* __restrict__ KFt,
    const float* __restrict__ UF, u16* __restrict__ UFt,
    const float* __restrict__ unknown, const float* __restrict__ known,
    int* __restrict__ idx_out, float* __restrict__ w_out)
{
    __shared__ __align__(16) char smem[32768];
    const int bid = blockIdx.x;
    const int t = threadIdx.x;

    if (bid < 128) {
        // flat f32 -> bf16 convert
        const float* X = (bid < 96) ? W1 : W2;
        u16* Y = (bid < 96) ? W1b : W2b;
        const int i = ((bid < 96) ? bid : (bid - 96)) * 256 + t;
        const float4 v = *(const float4*)&X[(size_t)i * 4];
        ushort4 o;
        o.x = f2bf(v.x); o.y = f2bf(v.y); o.z = f2bf(v.z); o.w = f2bf(v.w);
        *(ushort4*)&Y[(size_t)i * 4] = o;
    } else if (bid < 1664) {
        // transpose + convert: X (C, M) tile -> Y (M, C)
        const float* X;
        u16* Y;
        int C, M, m0, c0;
        if (bid < 640) {
            const int f = bid - 128;
            const int b = f >> 7, rem = f & 127;
            C = C2c; M = Mk; m0 = (rem >> 2) * 64; c0 = (rem & 3) * 64;
            X = KF + (size_t)b * C * M;
            Y = KFt + (size_t)b * M * C;
        } else {
            const int f = bid - 640;
            const int b = f >> 8, rem = f & 255;
            C = C1c; M = Nq; m0 = (rem >> 1) * 64; c0 = (rem & 1) * 64;
            X = UF + (size_t)b * C * M;
            Y = UFt + (size_t)b * M * C;
        }
        float (*T)[65] = (float(*)[65])smem;
        const int m4 = (t & 15) * 4, cr = t >> 4;
        #pragma unroll
        for (int i = 0; i < 4; ++i) {
            const float4 v = *(const float4*)&X[(size_t)(c0 + cr + i * 16) * M + m0 + m4];
            T[cr + i * 16][m4 + 0] = v.x;
            T[cr + i * 16][m4 + 1] = v.y;
            T[cr + i * 16][m4 + 2] = v.z;
            T[cr + i * 16][m4 + 3] = v.w;
        }
        __syncthreads();
        const int c4 = (t & 15) * 4, mr = t >> 4;
        #pragma unroll
        for (int i = 0; i < 4; ++i) {
            const int m = mr + i * 16;
            ushort4 o;
            o.x = f2bf(T[c4 + 0][m]);
            o.y = f2bf(T[c4 + 1][m]);
            o.z = f2bf(T[c4 + 2][m]);
            o.w = f2bf(T[c4 + 3][m]);
            *(ushort4*)&Y[(size_t)(m0 + m) * C + c0 + c4] = o;
        }
    } else {
        // 3-NN: exact f32 compare, 8 lanes/query
        float4* kp = (float4*)smem;  // (x, y, z, |k|^2), 32 KB
        const int kbid = bid - 1664;
        const int b = kbid >> 8;
        const int n0 = (kbid & 255) * 32;

        const float* kb = known + (size_t)b * Mk * 3;
        for (int i = t; i < Mk; i += 256) {
            const float x = kb[i * 3 + 0], y = kb[i * 3 + 1], z = kb[i * 3 + 2];
            kp[i] = make_float4(x, y, z, fmaf(x, x, fmaf(y, y, z * z)));
        }
        __syncthreads();

        const int q = n0 + (t >> 3);
        const int s = t & 7;
        const float* u = unknown + ((size_t)b * Nq + q) * 3;
        const float ux = u[0], uy = u[1], uz = u[2];
        const float nux = -2.0f * ux, nuy = -2.0f * uy, nuz = -2.0f * uz;
        const float uu = fmaf(ux, ux, fmaf(uy, uy, uz * uz));

        float d0 = 1e30f, d1 = 1e30f, d2 = 1e30f;
        int i0 = 0, i1 = 0, i2 = 0;
        auto ins = [&](float d, int i) {
            const bool c0 = d < d0, c1 = d < d1, c2 = d < d2;
            d2 = c1 ? d1 : (c2 ? d : d2);
            i2 = c1 ? i1 : (c2 ? i : i2);
            d1 = c0 ? d0 : (c1 ? d : d1);
            i1 = c0 ? i0 : (c1 ? i : i1);
            d0 = c0 ? d : d0;
            i0 = c0 ? i : i0;
        };

        for (int it = 0; it < Mk / 8; ++it) {
            const int m = it * 8 + s;
            const float4 p = kp[m];
            const float d = fmaf(nux, p.x, fmaf(nuy, p.y, fmaf(nuz, p.z, p.w)));
            ins(d, m);
        }
        #pragma unroll
        for (int off = 1; off <= 4; off <<= 1) {
            const float e0 = __shfl_xor(d0, off), e1 = __shfl_xor(d1, off), e2 = __shfl_xor(d2, off);
            const int j0 = __shfl_xor(i0, off), j1 = __shfl_xor(i1, off), j2 = __shfl_xor(i2, off);
            ins(e0, j0);
            ins(e1, j1);
            ins(e2, j2);
        }
        if (s == 0) {
            const float f0 = d0 + uu, f1 = d1 + uu, f2 = d2 + uu;
            const float r0 = 1.0f / (f0 + 1e-8f);
            const float r1 = 1.0f / (f1 + 1e-8f);
            const float r2 = 1.0f / (f2 + 1e-8f);
            const float inv = 1.0f / (r0 + r1 + r2);
            const size_t base = ((size_t)b * Nq + q) * 3;
            idx_out[base + 0] = i0;
            idx_out[base + 1] = i1;
            idx_out[base + 2] = i2;
            w_out[base + 0] = r0 * inv;
            w_out[base + 1] = r1 * inv;
            w_out[base + 2] = r2 * inv;
        }
    }
}

// ---------------- BN transform for staged B-operand (8 bf16) ----------------
__device__ __forceinline__ uint4 bnx(uint4 x, const float* scs, const float* bis, int k) {
    const u16* p = (const u16*)&x;
    u16 o[8];
    #pragma unroll
    for (int j = 0; j < 8; ++j)
        o[j] = f2bf(fmaxf(0.0f, fmaf(bf2f(p[j]), scs[k + j], bis[k + j])));
    return *(const uint4*)o;
}

// ================= bf16 MFMA bt-GEMM: C(M,N) = A(M,K) * Bt(N,K)^T =================
// 128x128 tile, BK=32, 4 waves (2x2 of 64x64), mfma_f32_16x16x32_bf16.
// STATS: 0=none, 1=per-col partial sums (over rows), 2=per-row partial sums (over cols)
// BNIN: apply scale/bias+relu to B-operand elements at LDS staging time (k-indexed)
template <int GATHER, int OUT_BF16, int STATS, int BNIN>
__global__ __launch_bounds__(256) void mfma_gemm(
    const u16* __restrict__ A, int lda, size_t sA,
    const u16* __restrict__ Bt, int ldb, size_t sB,
    void* __restrict__ Cout, int ldc, size_t sC,
    int nK,
    const u16* __restrict__ Ptb,
    const int* __restrict__ idx, const float* __restrict__ wgt, int nrows,
    const float* __restrict__ bn_s, const float* __restrict__ bn_b,
    float* __restrict__ partS, float* __restrict__ partQ)
{
    __shared__ u16 As[4096];
    __shared__ u16 Bs[4096];
    __shared__ float scs[256], bis[256];
    __shared__ float sS[2][128], sQ[2][128];

    const int b = blockIdx.z;
    const int m0 = blockIdx.x * 128, n0 = blockIdx.y * 128;
    const int t = threadIdx.x;
    const int l = t & 63, wv = t >> 6;
    const int wr = wv >> 1, wc = wv & 1;

    if (BNIN) {
        scs[t] = bn_s[t];
        bis[t] = bn_b[t];
    }

    const u16* Ab = A + (size_t)b * sA;
    const u16* Btb = Bt + (size_t)b * sB;
    const int rA0 = t >> 2, rA1 = (t + 256) >> 2;
    const int ko = (t & 3) * 8;

    f32x4 acc[4][4];
    const f32x4 z = {0.0f, 0.0f, 0.0f, 0.0f};
    #pragma unroll
    for (int i = 0; i < 4; ++i)
        #pragma unroll
        for (int j = 0; j < 4; ++j) acc[i][j] = z;

    uint4 a0 = *(const uint4*)&Ab[(size_t)(m0 + rA0) * lda + ko];
    uint4 a1 = *(const uint4*)&Ab[(size_t)(m0 + rA1) * lda + ko];
    uint4 b0 = *(const uint4*)&Btb[(size_t)(n0 + rA0) * ldb + ko];
    uint4 b1 = *(const uint4*)&Btb[(size_t)(n0 + rA1) * ldb + ko];
    if (BNIN) __syncthreads();  // scs/bis ready before first staging write

    for (int kt = 0; kt < nK; ++kt) {
        *(uint4*)&As[t * 8] = a0;
        *(uint4*)&As[(t + 256) * 8] = a1;
        if (BNIN) {
            const int k = kt * 32 + ko;
            *(uint4*)&Bs[t * 8] = bnx(b0, scs, bis, k);
            *(uint4*)&Bs[(t + 256) * 8] = bnx(b1, scs, bis, k);
        } else {
            *(uint4*)&Bs[t * 8] = b0;
            *(uint4*)&Bs[(t + 256) * 8] = b1;
        }
        __syncthreads();
        if (kt + 1 < nK) {
            const int k0 = (kt + 1) * 32;
            a0 = *(const uint4*)&Ab[(size_t)(m0 + rA0) * lda + k0 + ko];
            a1 = *(const uint4*)&Ab[(size_t)(m0 + rA1) * lda + k0 + ko];
            b0 = *(const uint4*)&Btb[(size_t)(n0 + rA0) * ldb + k0 + ko];
            b1 = *(const uint4*)&Btb[(size_t)(n0 + rA1) * ldb + k0 + ko];
        }
        bf16x8 af[4], bf[4];
        #pragma unroll
        for (int f = 0; f < 4; ++f) {
            af[f] = *(const bf16x8*)&As[(wr * 64 + f * 16 + (l & 15)) * 32 + (l >> 4) * 8];
            bf[f] = *(const bf16x8*)&Bs[(wc * 64 + f * 16 + (l & 15)) * 32 + (l >> 4) * 8];
        }
        #pragma unroll
        for (int i = 0; i < 4; ++i)
            #pragma unroll
            for (int j = 0; j < 4; ++j)
                acc[i][j] = __builtin_amdgcn_mfma_f32_16x16x32_bf16(af[i], bf[j], acc[i][j], 0, 0, 0);
        __syncthreads();
    }

    // -------- epilogue: store (+gather) (+stats accumulation) --------
    const int cb = l & 15;
    const int rg = (l >> 4) * 4;
    float sj[4] = {0, 0, 0, 0}, qj[4] = {0, 0, 0, 0};
    #pragma unroll
    for (int i = 0; i < 4; ++i) {
        #pragma unroll
        for (int r = 0; r < 4; ++r) {
            const int R = m0 + wr * 64 + i * 16 + rg + r;
            const u16 *P0 = nullptr, *P1 = nullptr, *P2 = nullptr;
            float w0 = 0.0f, w1 = 0.0f, w2 = 0.0f;
            if (GATHER) {
                const size_t ib = ((size_t)b * nrows + R) * 3;
                const int j0 = idx[ib], j1 = idx[ib + 1], j2 = idx[ib + 2];
                w0 = wgt[ib];
                w1 = wgt[ib + 1];
                w2 = wgt[ib + 2];
                const u16* Pb = Ptb + (size_t)b * Mk * 256;
                P0 = Pb + (size_t)j0 * 256;
                P1 = Pb + (size_t)j1 * 256;
                P2 = Pb + (size_t)j2 * 256;
            }
            #pragma unroll
            for (int j = 0; j < 4; ++j) {
                const int Cc = n0 + wc * 64 + j * 16 + cb;
                float v = acc[i][j][r];
                if (GATHER)
                    v += w0 * bf2f(P0[Cc]) + w1 * bf2f(P1[Cc]) + w2 * bf2f(P2[Cc]);
                if (OUT_BF16)
                    ((u16*)Cout)[(size_t)b * sC + (size_t)R * ldc + Cc] = f2bf(v);
                else
                    ((float*)Cout)[(size_t)b * sC + (size_t)R * ldc + Cc] = v;
                if (STATS == 1) {
                    sj[j] += v;
                    qj[j] += v * v;
                }
                if (STATS == 2) acc[i][j][r] = v;  // keep for row-stats below
            }
        }
    }

    if (STATS == 1) {
        // per-column sums over this block's 128 rows
        #pragma unroll
        for (int j = 0; j < 4; ++j) {
            float s = sj[j], q = qj[j];
            s += __shfl_xor(s, 16); s += __shfl_xor(s, 32);
            q += __shfl_xor(q, 16); q += __shfl_xor(q, 32);
            if (l < 16) {
                sS[wr][wc * 64 + j * 16 + l] = s;
                sQ[wr][wc * 64 + j * 16 + l] = q;
            }
        }
        __syncthreads();
        if (t < 128) {
            const float S = sS[0][t] + sS[1][t];
            const float Q = sQ[0][t] + sQ[1][t];
            const int pblk = blockIdx.z * gridDim.x + blockIdx.x;
            partS[(size_t)pblk * 256 + blockIdx.y * 128 + t] = S;
            partQ[(size_t)pblk * 256 + blockIdx.y * 128 + t] = Q;
        }
    }
    if (STATS == 2) {
        // per-row sums over this block's 128 cols
        #pragma unroll
        for (int i = 0; i < 4; ++i) {
            #pragma unroll
            for (int r = 0; r < 4; ++r) {
                float s = acc[i][0][r] + acc[i][1][r] + acc[i][2][r] + acc[i][3][r];
                float q = acc[i][0][r] * acc[i][0][r] + acc[i][1][r] * acc[i][1][r] +
                          acc[i][2][r] * acc[i][2][r] + acc[i][3][r] * acc[i][3][r];
                s += __shfl_xor(s, 1); s += __shfl_xor(s, 2);
                s += __shfl_xor(s, 4); s += __shfl_xor(s, 8);
                q += __shfl_xor(q, 1); q += __shfl_xor(q, 2);
                q += __shfl_xor(q, 4); q += __shfl_xor(q, 8);
                if ((l & 15) == 0) {
                    const int row = wr * 64 + i * 16 + (l >> 4) * 4 + r;
                    sS[wc][row] = s;
                    sQ[wc][row] = q;
                }
            }
        }
        __syncthreads();
        if (t < 128) {
            const float S = sS[0][t] + sS[1][t];
            const float Q = sQ[0][t] + sQ[1][t];
            const int pblk = blockIdx.z * gridDim.y + blockIdx.y;
            partS[(size_t)pblk * 128 + t] = S;
            partQ[(size_t)pblk * 128 + t] = Q;
        }
    }
}

// ---------------- BN1 finalize: reduce partials -> scale/bias ----------------
__global__ __launch_bounds__(1024) void bn_finalize(
    const float* __restrict__ pS, const float* __restrict__ pQ,
    const float* __restrict__ g, const float* __restrict__ beta,
    float* __restrict__ scale, float* __restrict__ bias,
    int C, int np, float cnt)
{
    __shared__ float rs[1024], rq[1024];
    const int t = threadIdx.x;
    const int c = t & (C - 1);
    const int sl = t / C;
    const int nsl = 1024 / C;
    float s = 0.0f, q = 0.0f;
    for (int i = sl; i < np; i += nsl) {
        s += pS[(size_t)i * C + c];
        q += pQ[(size_t)i * C + c];
    }
    rs[t] = s;
    rq[t] = q;
    __syncthreads();
    if (t < C) {
        for (int k = 1; k < nsl; ++k) {
            s += rs[t + k * C];
            q += rq[t + k * C];
        }
        const float mean = s / cnt;
        const float var = q / cnt - mean * mean;
        const float r = rsqrtf(var + 1e-5f);
        const float sc = g[t] * r;
        scale[t] = sc;
        bias[t] = beta[t] - mean * sc;
    }
}

// ---------------- fused BN2 finalize + apply: each block reduces partials for its channel ----------------
__global__ __launch_bounds__(256) void bn2_apply_kernel(
    float* __restrict__ Y,
    const float* __restrict__ pS, const float* __restrict__ pQ,
    const float* __restrict__ g, const float* __restrict__ beta)
{
    __shared__ float rs[256], rq[256];
    const int t = threadIdx.x;
    const size_t base = (size_t)blockIdx.x * 1024;
    const int c = (int)((base / Nq) % H2c);

    rs[t] = pS[(size_t)t * 128 + c];
    rq[t] = pQ[(size_t)t * 128 + c];
    __syncthreads();
    for (int off = 128; off > 0; off >>= 1) {
        if (t < off) {
            rs[t] += rs[t + off];
            rq[t] += rq[t + off];
        }
        __syncthreads();
    }
    if (t == 0) {
        const float cnt = (float)(Bn * Nq);
        const float mean = rs[0] / cnt;
        const float var = rq[0] / cnt - mean * mean;
        const float r = rsqrtf(var + 1e-5f);
        const float sc = g[c] * r;
        rs[0] = sc;
        rq[0] = beta[c] - mean * sc;
    }
    __syncthreads();
    const float sc = rs[0], bi = rq[0];
    float4 v = *(float4*)&Y[base + t * 4];
    v.x = fmaxf(0.0f, fmaf(v.x, sc, bi));
    v.y = fmaxf(0.0f, fmaf(v.y, sc, bi));
    v.z = fmaxf(0.0f, fmaf(v.z, sc, bi));
    v.w = fmaxf(0.0f, fmaf(v.w, sc, bi));
    *(float4*)&Y[base + t * 4] = v;
}

extern "C" void kernel_launch(void* const* d_in, const int* in_sizes, int n_in,
                              void* d_out, int out_size, void* d_ws, size_t ws_size,
                              hipStream_t stream) {
    const float* unknown = (const float*)d_in[0];      // (B, Nq, 3)
    const float* known = (const float*)d_in[1];        // (B, Mk, 3)
    const float* unknow_feats = (const float*)d_in[2]; // (B, C1, Nq)
    const float* known_feats = (const float*)d_in[3];  // (B, C2, Mk)
    const float* W1 = (const float*)d_in[4];           // (256, 384)
    const float* g1 = (const float*)d_in[5];
    const float* b1 = (const float*)d_in[6];
    const float* W2 = (const float*)d_in[7];           // (128, 256)
    const float* g2 = (const float*)d_in[8];
    const float* b2 = (const float*)d_in[9];
    float* out = (float*)d_out;                        // (B, 128, Nq)

    // workspace layout (all 16B aligned)
    char* w = (char*)d_ws;
    u16* KFt = (u16*)w; w += (size_t)Bn * Mk * C2c * 2;   // (B, 2048, 256) bf16
    u16* UFt = (u16*)w; w += (size_t)Bn * Nq * C1c * 2;   // (B, 8192, 128) bf16
    u16* W1b = (u16*)w; w += (size_t)H1c * 384 * 2;
    u16* W2b = (u16*)w; w += (size_t)H2c * H1c * 2;
    u16* Ptb = (u16*)w; w += (size_t)Bn * Mk * H1c * 2;   // (B, 2048, 256) bf16
    u16* y1b = (u16*)w; w += (size_t)Bn * Nq * H1c * 2;   // (B, 8192, 256) bf16
    int* idx = (int*)w; w += (size_t)Bn * Nq * 3 * 4;
    float* wgt = (float*)w; w += (size_t)Bn * Nq * 3 * 4;
    float* pS1 = (float*)w; w += (size_t)256 * 256 * 4;   // [pblk=256][ch=256]
    float* pQ1 = (float*)w; w += (size_t)256 * 256 * 4;
    float* pS2 = (float*)w; w += (size_t)256 * 128 * 4;   // [pblk=256][ch=128]
    float* pQ2 = (float*)w; w += (size_t)256 * 128 * 4;
    float* scale1 = (float*)w; w += 1024;
    float* bias1 = (float*)w; w += 1024;

    // 1) fused prep (weight cvt + feat transposes) + 3-NN
    prep_knn_kernel<<<2688, 256, 0, stream>>>(W1, W2, W1b, W2b,
                                              known_feats, KFt, unknow_feats, UFt,
                                              unknown, known, idx, wgt);

    // 2) Ptb(b,m,h) = KFt(b,m,:) @ W1[:, :256]^T
    mfma_gemm<0, 1, 0, 0><<<dim3(Mk / 128, H1c / 128, Bn), 256, 0, stream>>>(
        KFt, C2c, (size_t)Mk * C2c,
        W1b, 384, 0,
        Ptb, H1c, (size_t)Mk * H1c,
        C2c / 32, nullptr, nullptr, nullptr, 0,
        nullptr, nullptr, nullptr, nullptr);

    // 3) y1b(b,n,h) = UFt(b,n,:) @ W1[:, 256:]^T + gather(Ptb)  [+ BN1 partial stats]
    mfma_gemm<1, 1, 1, 0><<<dim3(Nq / 128, H1c / 128, Bn), 256, 0, stream>>>(
        UFt, C1c, (size_t)Nq * C1c,
        W1b + C2c, 384, 0,
        y1b, H1c, (size_t)Nq * H1c,
        C1c / 32, Ptb, idx, wgt, Nq,
        nullptr, nullptr, pS1, pQ1);

    // 4) BN1 finalize -> scale1/bias1
    bn_finalize<<<1, 1024, 0, stream>>>(pS1, pQ1, g1, b1, scale1, bias1,
                                        H1c, 256, (float)(Bn * Nq));

    // 5) out(b,o,n) = W2(o,:) @ relu(bn1(y1b(b,n,:)))^T  [+ BN2 partial stats]
    mfma_gemm<0, 0, 2, 1><<<dim3(1, Nq / 128, Bn), 256, 0, stream>>>(
        W2b, H1c, 0,
        y1b, H1c, (size_t)Nq * H1c,
        out, Nq, (size_t)H2c * Nq,
        H1c / 32, nullptr, nullptr, nullptr, 0,
        scale1, bias1, pS2, pQ2);

    // 6) BN2 finalize (per-block) + apply in place
    bn2_apply_kernel<<<(Bn * H2c * Nq) / 1024, 256, 0, stream>>>(out, pS2, pQ2, g2, b2);
}

// Round 6
// 107.856 us; speedup vs baseline: 2.2056x; 1.0134x over previous
//
#include <hip/hip_runtime.h>
#include <hip/hip_bf16.h>
#include <cstdint>
#include <cstddef>

typedef unsigned short u16;
typedef __attribute__((ext_vector_type(8))) short bf16x8;
typedef __attribute__((ext_vector_type(4))) float f32x4;

constexpr int Bn = 4;
constexpr int Nq = 8192;
constexpr int Mk = 2048;
constexpr int C1c = 128;
constexpr int C2c = 256;
constexpr int H1c = 256;
constexpr int H2c = 128;

__device__ __forceinline__ float bf2f(u16 u) {
    union { uint32_t i; float f; } v;
    v.i = (uint32_t)u << 16;
    return v.f;
}
__device__ __forceinline__ u16 f2bf(float f) {
    const uint32_t x = __float_as_uint(f);
    return (u16)((x + 0x7FFFu + ((x >> 16) & 1u)) >> 16);
}

// ================= fused knn + prep (cvt W1/W2, transpose KF, transpose UF) =================
// block ranges (knn FIRST so the long pole starts at t=0):
// [0,1024) knn | [1024,1120) cvt W1 | [1120,1152) cvt W2 | [1152,1664) KF | [1664,2688) UF
__global__ __launch_bounds__(256) void knn_prep_kernel(
    const float* __restrict__ W1, const float* __restrict__ W2,
    u16* __restrict__ W1b, u16* __restrict__ W2b,
    const float* __restrict__ KF, u16* __restrict__ KFt,
    const float* __restrict__ UF, u16* __restrict__ UFt,
    const float* __restrict__ unknown, const float* __restrict__ known,
    int* __restrict__ idx_out, float* __restrict__ w_out)
{
    __shared__ __align__(16) char smem[32768];
    const int bid = blockIdx.x;
    const int t = threadIdx.x;

    if (bid < 1024) {
        // ---- 3-NN: exact f32 compare, 8 lanes/query ----
        float4* kp = (float4*)smem;  // (x, y, z, |k|^2), 32 KB
        const int b = bid >> 8;
        const int n0 = (bid & 255) * 32;

        const float* kb = known + (size_t)b * Mk * 3;
        for (int i = t; i < Mk; i += 256) {
            const float x = kb[i * 3 + 0], y = kb[i * 3 + 1], z = kb[i * 3 + 2];
            kp[i] = make_float4(x, y, z, fmaf(x, x, fmaf(y, y, z * z)));
        }
        __syncthreads();

        const int q = n0 + (t >> 3);
        const int s = t & 7;
        const float* u = unknown + ((size_t)b * Nq + q) * 3;
        const float ux = u[0], uy = u[1], uz = u[2];
        const float nux = -2.0f * ux, nuy = -2.0f * uy, nuz = -2.0f * uz;
        const float uu = fmaf(ux, ux, fmaf(uy, uy, uz * uz));

        // track d' = |k|^2 - 2 u.k  (ordering identical to true squared distance)
        float d0 = 1e30f, d1 = 1e30f, d2 = 1e30f;
        int i0 = 0, i1 = 0, i2 = 0;

        // sorted-3 insert: distances via min/med3 (3 ops), indices via exact-compare cndmask
        auto ins = [&](float d, int i) {
            const bool c0 = d < d0, c1 = d < d1, c2 = d < d2;
            const float nd0 = fminf(d0, d);
            const float nd1 = __builtin_amdgcn_fmed3f(d0, d, d1);
            const float nd2 = __builtin_amdgcn_fmed3f(d1, d, d2);
            i2 = c1 ? i1 : (c2 ? i : i2);
            i1 = c0 ? i0 : (c1 ? i : i1);
            i0 = c0 ? i : i0;
            d0 = nd0; d1 = nd1; d2 = nd2;
        };

        #pragma unroll 8
        for (int it = 0; it < Mk / 8; ++it) {
            const int m = it * 8 + s;  // 8 consecutive float4 slots per step: conflict-free
            const float4 p = kp[m];
            const float d = fmaf(nux, p.x, fmaf(nuy, p.y, fmaf(nuz, p.z, p.w)));
            ins(d, m);
        }
        #pragma unroll
        for (int off = 1; off <= 4; off <<= 1) {
            const float e0 = __shfl_xor(d0, off), e1 = __shfl_xor(d1, off), e2 = __shfl_xor(d2, off);
            const int j0 = __shfl_xor(i0, off), j1 = __shfl_xor(i1, off), j2 = __shfl_xor(i2, off);
            ins(e0, j0);
            ins(e1, j1);
            ins(e2, j2);
        }
        if (s == 0) {
            const float f0 = d0 + uu, f1 = d1 + uu, f2 = d2 + uu;
            const float r0 = 1.0f / (f0 + 1e-8f);
            const float r1 = 1.0f / (f1 + 1e-8f);
            const float r2 = 1.0f / (f2 + 1e-8f);
            const float inv = 1.0f / (r0 + r1 + r2);
            const size_t base = ((size_t)b * Nq + q) * 3;
            idx_out[base + 0] = i0;
            idx_out[base + 1] = i1;
            idx_out[base + 2] = i2;
            w_out[base + 0] = r0 * inv;
            w_out[base + 1] = r1 * inv;
            w_out[base + 2] = r2 * inv;
        }
    } else if (bid < 1152) {
        // ---- flat f32 -> bf16 convert (weights) ----
        const int cb = bid - 1024;
        const float* X = (cb < 96) ? W1 : W2;
        u16* Y = (cb < 96) ? W1b : W2b;
        const int i = ((cb < 96) ? cb : (cb - 96)) * 256 + t;
        const float4 v = *(const float4*)&X[(size_t)i * 4];
        ushort4 o;
        o.x = f2bf(v.x); o.y = f2bf(v.y); o.z = f2bf(v.z); o.w = f2bf(v.w);
        *(ushort4*)&Y[(size_t)i * 4] = o;
    } else {
        // ---- transpose + convert: X (C, M) tile -> Y (M, C) ----
        const float* X;
        u16* Y;
        int C, M, m0, c0;
        if (bid < 1664) {
            const int f = bid - 1152;
            const int b = f >> 7, rem = f & 127;
            C = C2c; M = Mk; m0 = (rem >> 2) * 64; c0 = (rem & 3) * 64;
            X = KF + (size_t)b * C * M;
            Y = KFt + (size_t)b * M * C;
        } else {
            const int f = bid - 1664;
            const int b = f >> 8, rem = f & 255;
            C = C1c; M = Nq; m0 = (rem >> 1) * 64; c0 = (rem & 1) * 64;
            X = UF + (size_t)b * C * M;
            Y = UFt + (size_t)b * M * C;
        }
        float (*T)[65] = (float(*)[65])smem;
        const int m4 = (t & 15) * 4, cr = t >> 4;
        #pragma unroll
        for (int i = 0; i < 4; ++i) {
            const float4 v = *(const float4*)&X[(size_t)(c0 + cr + i * 16) * M + m0 + m4];
            T[cr + i * 16][m4 + 0] = v.x;
            T[cr + i * 16][m4 + 1] = v.y;
            T[cr + i * 16][m4 + 2] = v.z;
            T[cr + i * 16][m4 + 3] = v.w;
        }
        __syncthreads();
        const int c4 = (t & 15) * 4, mr = t >> 4;
        #pragma unroll
        for (int i = 0; i < 4; ++i) {
            const int m = mr + i * 16;
            ushort4 o;
            o.x = f2bf(T[c4 + 0][m]);
            o.y = f2bf(T[c4 + 1][m]);
            o.z = f2bf(T[c4 + 2][m]);
            o.w = f2bf(T[c4 + 3][m]);
            *(ushort4*)&Y[(size_t)(m0 + m) * C + c0 + c4] = o;
        }
    }
}

// ---------------- BN transform for staged B-operand (8 bf16) ----------------
__device__ __forceinline__ uint4 bnx(uint4 x, const float* scs, const float* bis, int k) {
    const u16* p = (const u16*)&x;
    u16 o[8];
    #pragma unroll
    for (int j = 0; j < 8; ++j)
        o[j] = f2bf(fmaxf(0.0f, fmaf(bf2f(p[j]), scs[k + j], bis[k + j])));
    return *(const uint4*)o;
}

// ================= bf16 MFMA bt-GEMM: C(M,N) = A(M,K) * Bt(N,K)^T =================
// 128x128 tile, BK=32, 4 waves (2x2 of 64x64), mfma_f32_16x16x32_bf16.
// STATS: 0=none, 1=per-col partial sums (over rows), 2=per-row partial sums (over cols)
// BNIN: apply scale/bias+relu to B-operand elements at LDS staging time (k-indexed)
template <int GATHER, int OUT_BF16, int STATS, int BNIN>
__global__ __launch_bounds__(256) void mfma_gemm(
    const u16* __restrict__ A, int lda, size_t sA,
    const u16* __restrict__ Bt, int ldb, size_t sB,
    void* __restrict__ Cout, int ldc, size_t sC,
    int nK,
    const u16* __restrict__ Ptb,
    const int* __restrict__ idx, const float* __restrict__ wgt, int nrows,
    const float* __restrict__ bn_s, const float* __restrict__ bn_b,
    float* __restrict__ partS, float* __restrict__ partQ)
{
    __shared__ u16 As[4096];
    __shared__ u16 Bs[4096];
    __shared__ float scs[256], bis[256];
    __shared__ float sS[2][128], sQ[2][128];

    const int b = blockIdx.z;
    const int m0 = blockIdx.x * 128, n0 = blockIdx.y * 128;
    const int t = threadIdx.x;
    const int l = t & 63, wv = t >> 6;
    const int wr = wv >> 1, wc = wv & 1;

    if (BNIN) {
        scs[t] = bn_s[t];
        bis[t] = bn_b[t];
    }

    const u16* Ab = A + (size_t)b * sA;
    const u16* Btb = Bt + (size_t)b * sB;
    const int rA0 = t >> 2, rA1 = (t + 256) >> 2;
    const int ko = (t & 3) * 8;

    f32x4 acc[4][4];
    const f32x4 z = {0.0f, 0.0f, 0.0f, 0.0f};
    #pragma unroll
    for (int i = 0; i < 4; ++i)
        #pragma unroll
        for (int j = 0; j < 4; ++j) acc[i][j] = z;

    uint4 a0 = *(const uint4*)&Ab[(size_t)(m0 + rA0) * lda + ko];
    uint4 a1 = *(const uint4*)&Ab[(size_t)(m0 + rA1) * lda + ko];
    uint4 b0 = *(const uint4*)&Btb[(size_t)(n0 + rA0) * ldb + ko];
    uint4 b1 = *(const uint4*)&Btb[(size_t)(n0 + rA1) * ldb + ko];
    if (BNIN) __syncthreads();  // scs/bis ready before first staging write

    for (int kt = 0; kt < nK; ++kt) {
        *(uint4*)&As[t * 8] = a0;
        *(uint4*)&As[(t + 256) * 8] = a1;
        if (BNIN) {
            const int k = kt * 32 + ko;
            *(uint4*)&Bs[t * 8] = bnx(b0, scs, bis, k);
            *(uint4*)&Bs[(t + 256) * 8] = bnx(b1, scs, bis, k);
        } else {
            *(uint4*)&Bs[t * 8] = b0;
            *(uint4*)&Bs[(t + 256) * 8] = b1;
        }
        __syncthreads();
        if (kt + 1 < nK) {
            const int k0 = (kt + 1) * 32;
            a0 = *(const uint4*)&Ab[(size_t)(m0 + rA0) * lda + k0 + ko];
            a1 = *(const uint4*)&Ab[(size_t)(m0 + rA1) * lda + k0 + ko];
            b0 = *(const uint4*)&Btb[(size_t)(n0 + rA0) * ldb + k0 + ko];
            b1 = *(const uint4*)&Btb[(size_t)(n0 + rA1) * ldb + k0 + ko];
        }
        bf16x8 af[4], bf[4];
        #pragma unroll
        for (int f = 0; f < 4; ++f) {
            af[f] = *(const bf16x8*)&As[(wr * 64 + f * 16 + (l & 15)) * 32 + (l >> 4) * 8];
            bf[f] = *(const bf16x8*)&Bs[(wc * 64 + f * 16 + (l & 15)) * 32 + (l >> 4) * 8];
        }
        #pragma unroll
        for (int i = 0; i < 4; ++i)
            #pragma unroll
            for (int j = 0; j < 4; ++j)
                acc[i][j] = __builtin_amdgcn_mfma_f32_16x16x32_bf16(af[i], bf[j], acc[i][j], 0, 0, 0);
        __syncthreads();
    }

    // -------- epilogue: store (+gather) (+stats accumulation) --------
    const int cb = l & 15;
    const int rg = (l >> 4) * 4;
    float sj[4] = {0, 0, 0, 0}, qj[4] = {0, 0, 0, 0};
    #pragma unroll
    for (int i = 0; i < 4; ++i) {
        #pragma unroll
        for (int r = 0; r < 4; ++r) {
            const int R = m0 + wr * 64 + i * 16 + rg + r;
            const u16 *P0 = nullptr, *P1 = nullptr, *P2 = nullptr;
            float w0 = 0.0f, w1 = 0.0f, w2 = 0.0f;
            if (GATHER) {
                const size_t ib = ((size_t)b * nrows + R) * 3;
                const int j0 = idx[ib], j1 = idx[ib + 1], j2 = idx[ib + 2];
                w0 = wgt[ib];
                w1 = wgt[ib + 1];
                w2 = wgt[ib + 2];
                const u16* Pb = Ptb + (size_t)b * Mk * 256;
                P0 = Pb + (size_t)j0 * 256;
                P1 = Pb + (size_t)j1 * 256;
                P2 = Pb + (size_t)j2 * 256;
            }
            #pragma unroll
            for (int j = 0; j < 4; ++j) {
                const int Cc = n0 + wc * 64 + j * 16 + cb;
                float v = acc[i][j][r];
                if (GATHER)
                    v += w0 * bf2f(P0[Cc]) + w1 * bf2f(P1[Cc]) + w2 * bf2f(P2[Cc]);
                if (OUT_BF16)
                    ((u16*)Cout)[(size_t)b * sC + (size_t)R * ldc + Cc] = f2bf(v);
                else
                    ((float*)Cout)[(size_t)b * sC + (size_t)R * ldc + Cc] = v;
                if (STATS == 1) {
                    sj[j] += v;
                    qj[j] += v * v;
                }
                if (STATS == 2) acc[i][j][r] = v;  // keep for row-stats below
            }
        }
    }

    if (STATS == 1) {
        #pragma unroll
        for (int j = 0; j < 4; ++j) {
            float s = sj[j], q = qj[j];
            s += __shfl_xor(s, 16); s += __shfl_xor(s, 32);
            q += __shfl_xor(q, 16); q += __shfl_xor(q, 32);
            if (l < 16) {
                sS[wr][wc * 64 + j * 16 + l] = s;
                sQ[wr][wc * 64 + j * 16 + l] = q;
            }
        }
        __syncthreads();
        if (t < 128) {
            const float S = sS[0][t] + sS[1][t];
            const float Q = sQ[0][t] + sQ[1][t];
            const int pblk = blockIdx.z * gridDim.x + blockIdx.x;
            partS[(size_t)pblk * 256 + blockIdx.y * 128 + t] = S;
            partQ[(size_t)pblk * 256 + blockIdx.y * 128 + t] = Q;
        }
    }
    if (STATS == 2) {
        #pragma unroll
        for (int i = 0; i < 4; ++i) {
            #pragma unroll
            for (int r = 0; r < 4; ++r) {
                float s = acc[i][0][r] + acc[i][1][r] + acc[i][2][r] + acc[i][3][r];
                float q = acc[i][0][r] * acc[i][0][r] + acc[i][1][r] * acc[i][1][r] +
                          acc[i][2][r] * acc[i][2][r] + acc[i][3][r] * acc[i][3][r];
                s += __shfl_xor(s, 1); s += __shfl_xor(s, 2);
                s += __shfl_xor(s, 4); s += __shfl_xor(s, 8);
                q += __shfl_xor(q, 1); q += __shfl_xor(q, 2);
                q += __shfl_xor(q, 4); q += __shfl_xor(q, 8);
                if ((l & 15) == 0) {
                    const int row = wr * 64 + i * 16 + (l >> 4) * 4 + r;
                    sS[wc][row] = s;
                    sQ[wc][row] = q;
                }
            }
        }
        __syncthreads();
        if (t < 128) {
            const float S = sS[0][t] + sS[1][t];
            const float Q = sQ[0][t] + sQ[1][t];
            const int pblk = blockIdx.z * gridDim.y + blockIdx.y;
            partS[(size_t)pblk * 128 + t] = S;
            partQ[(size_t)pblk * 128 + t] = Q;
        }
    }
}

// ---------------- BN1 finalize: reduce partials -> scale/bias ----------------
__global__ __launch_bounds__(1024) void bn_finalize(
    const float* __restrict__ pS, const float* __restrict__ pQ,
    const float* __restrict__ g, const float* __restrict__ beta,
    float* __restrict__ scale, float* __restrict__ bias,
    int C, int np, float cnt)
{
    __shared__ float rs[1024], rq[1024];
    const int t = threadIdx.x;
    const int c = t & (C - 1);
    const int sl = t / C;
    const int nsl = 1024 / C;
    float s = 0.0f, q = 0.0f;
    for (int i = sl; i < np; i += nsl) {
        s += pS[(size_t)i * C + c];
        q += pQ[(size_t)i * C + c];
    }
    rs[t] = s;
    rq[t] = q;
    __syncthreads();
    if (t < C) {
        for (int k = 1; k < nsl; ++k) {
            s += rs[t + k * C];
            q += rq[t + k * C];
        }
        const float mean = s / cnt;
        const float var = q / cnt - mean * mean;
        const float r = rsqrtf(var + 1e-5f);
        const float sc = g[t] * r;
        scale[t] = sc;
        bias[t] = beta[t] - mean * sc;
    }
}

// ---------------- fused BN2 finalize + apply ----------------
__global__ __launch_bounds__(256) void bn2_apply_kernel(
    float* __restrict__ Y,
    const float* __restrict__ pS, const float* __restrict__ pQ,
    const float* __restrict__ g, const float* __restrict__ beta)
{
    __shared__ float rs[256], rq[256];
    const int t = threadIdx.x;
    const size_t base = (size_t)blockIdx.x * 1024;
    const int c = (int)((base / Nq) % H2c);

    rs[t] = pS[(size_t)t * 128 + c];
    rq[t] = pQ[(size_t)t * 128 + c];
    __syncthreads();
    for (int off = 128; off > 0; off >>= 1) {
        if (t < off) {
            rs[t] += rs[t + off];
            rq[t] += rq[t + off];
        }
        __syncthreads();
    }
    if (t == 0) {
        const float cnt = (float)(Bn * Nq);
        const float mean = rs[0] / cnt;
        const float var = rq[0] / cnt - mean * mean;
        const float r = rsqrtf(var + 1e-5f);
        const float sc = g[c] * r;
        rs[0] = sc;
        rq[0] = beta[c] - mean * sc;
    }
    __syncthreads();
    const float sc = rs[0], bi = rq[0];
    float4 v = *(float4*)&Y[base + t * 4];
    v.x = fmaxf(0.0f, fmaf(v.x, sc, bi));
    v.y = fmaxf(0.0f, fmaf(v.y, sc, bi));
    v.z = fmaxf(0.0f, fmaf(v.z, sc, bi));
    v.w = fmaxf(0.0f, fmaf(v.w, sc, bi));
    *(float4*)&Y[base + t * 4] = v;
}

extern "C" void kernel_launch(void* const* d_in, const int* in_sizes, int n_in,
                              void* d_out, int out_size, void* d_ws, size_t ws_size,
                              hipStream_t stream) {
    const float* unknown = (const float*)d_in[0];      // (B, Nq, 3)
    const float* known = (const float*)d_in[1];        // (B, Mk, 3)
    const float* unknow_feats = (const float*)d_in[2]; // (B, C1, Nq)
    const float* known_feats = (const float*)d_in[3];  // (B, C2, Mk)
    const float* W1 = (const float*)d_in[4];           // (256, 384)
    const float* g1 = (const float*)d_in[5];
    const float* b1 = (const float*)d_in[6];
    const float* W2 = (const float*)d_in[7];           // (128, 256)
    const float* g2 = (const float*)d_in[8];
    const float* b2 = (const float*)d_in[9];
    float* out = (float*)d_out;                        // (B, 128, Nq)

    // workspace layout (all 16B aligned)
    char* w = (char*)d_ws;
    u16* KFt = (u16*)w; w += (size_t)Bn * Mk * C2c * 2;   // (B, 2048, 256) bf16
    u16* UFt = (u16*)w; w += (size_t)Bn * Nq * C1c * 2;   // (B, 8192, 128) bf16
    u16* W1b = (u16*)w; w += (size_t)H1c * 384 * 2;
    u16* W2b = (u16*)w; w += (size_t)H2c * H1c * 2;
    u16* Ptb = (u16*)w; w += (size_t)Bn * Mk * H1c * 2;   // (B, 2048, 256) bf16
    u16* y1b = (u16*)w; w += (size_t)Bn * Nq * H1c * 2;   // (B, 8192, 256) bf16
    int* idx = (int*)w; w += (size_t)Bn * Nq * 3 * 4;
    float* wgt = (float*)w; w += (size_t)Bn * Nq * 3 * 4;
    float* pS1 = (float*)w; w += (size_t)256 * 256 * 4;   // [pblk=256][ch=256]
    float* pQ1 = (float*)w; w += (size_t)256 * 256 * 4;
    float* pS2 = (float*)w; w += (size_t)256 * 128 * 4;   // [pblk=256][ch=128]
    float* pQ2 = (float*)w; w += (size_t)256 * 128 * 4;
    float* scale1 = (float*)w; w += 1024;
    float* bias1 = (float*)w; w += 1024;

    // 1) fused knn (first!) + prep (weight cvt + feat transposes)
    knn_prep_kernel<<<2688, 256, 0, stream>>>(W1, W2, W1b, W2b,
                                              known_feats, KFt, unknow_feats, UFt,
                                              unknown, known, idx, wgt);

    // 2) Ptb(b,m,h) = KFt(b,m,:) @ W1[:, :256]^T
    mfma_gemm<0, 1, 0, 0><<<dim3(Mk / 128, H1c / 128, Bn), 256, 0, stream>>>(
        KFt, C2c, (size_t)Mk * C2c,
        W1b, 384, 0,
        Ptb, H1c, (size_t)Mk * H1c,
        C2c / 32, nullptr, nullptr, nullptr, 0,
        nullptr, nullptr, nullptr, nullptr);

    // 3) y1b(b,n,h) = UFt(b,n,:) @ W1[:, 256:]^T + gather(Ptb)  [+ BN1 partial stats]
    mfma_gemm<1, 1, 1, 0><<<dim3(Nq / 128, H1c / 128, Bn), 256, 0, stream>>>(
        UFt, C1c, (size_t)Nq * C1c,
        W1b + C2c, 384, 0,
        y1b, H1c, (size_t)Nq * H1c,
        C1c / 32, Ptb, idx, wgt, Nq,
        nullptr, nullptr, pS1, pQ1);

    // 4) BN1 finalize -> scale1/bias1
    bn_finalize<<<1, 1024, 0, stream>>>(pS1, pQ1, g1, b1, scale1, bias1,
                                        H1c, 256, (float)(Bn * Nq));

    // 5) out(b,o,n) = W2(o,:) @ relu(bn1(y1b(b,n,:)))^T  [+ BN2 partial stats]
    mfma_gemm<0, 0, 2, 1><<<dim3(1, Nq / 128, Bn), 256, 0, stream>>>(
        W2b, H1c, 0,
        y1b, H1c, (size_t)Nq * H1c,
        out, Nq, (size_t)H2c * Nq,
        H1c / 32, nullptr, nullptr, nullptr, 0,
        scale1, bias1, pS2, pQ2);

    // 6) BN2 finalize (per-block) + apply in place
    bn2_apply_kernel<<<(Bn * H2c * Nq) / 1024, 256, 0, stream>>>(out, pS2, pQ2, g2, b2);
}